// Round 13
// baseline (276.370 us; speedup 1.0000x reference)
//
#include <hip/hip_runtime.h>
#include <stdint.h>

#define D_MODEL 1024
#define NHEAD   16
#define DK      64
#define BATCH   4
#define SEQ     2048
#define MTOT    (BATCH*SEQ)   // 8192
#define KVB     64
#define NT      (SEQ/KVB)     // 32

typedef __attribute__((ext_vector_type(4)))  float  f32x4;
typedef __attribute__((ext_vector_type(16))) float  f32x16;
typedef __attribute__((ext_vector_type(8)))  __bf16 bf16x8;
typedef __attribute__((ext_vector_type(8)))  unsigned short u16x8;
typedef __attribute__((ext_vector_type(4)))  unsigned int u32x4;

// Q scale: 1/sqrt(dk) * log2(e)  (softmax computed in exp2 domain)
#define QSCALE 0.1803368801111244f

__device__ __forceinline__ unsigned short f2bf(float f) {
    unsigned u = __builtin_bit_cast(unsigned, f);
    u += 0x7fffu + ((u >> 16) & 1u);
    return (unsigned short)(u >> 16);
}

// ---------------- convert x (fp32 -> bf16) ----------------
__global__ __launch_bounds__(256) void cvt_x_kernel(const float* __restrict__ x,
                                                    unsigned short* __restrict__ xb) {
    size_t i = ((size_t)blockIdx.x * 256 + threadIdx.x) * 8;
    f32x4 a = *(const f32x4*)(x + i);
    f32x4 b = *(const f32x4*)(x + i + 4);
    u16x8 o;
    o[0] = f2bf(a[0]); o[1] = f2bf(a[1]); o[2] = f2bf(a[2]); o[3] = f2bf(a[3]);
    o[4] = f2bf(b[0]); o[5] = f2bf(b[1]); o[6] = f2bf(b[2]); o[7] = f2bf(b[3]);
    *(u16x8*)(xb + i) = o;
}

// ------------- transpose+convert W[k][n] -> W^T[n][k] bf16 -------------
__global__ __launch_bounds__(256) void cvt_wt_kernel(const float* __restrict__ Wq,
                                                     const float* __restrict__ Wk,
                                                     const float* __restrict__ Wv,
                                                     unsigned short* __restrict__ wt) {
    __shared__ float tile[32][33];
    int mat = blockIdx.z;
    const float* W = (mat == 0) ? Wq : (mat == 1) ? Wk : Wv;
    int n0 = blockIdx.x * 32;
    int k0 = blockIdx.y * 32;
    int tx = threadIdx.x;       // 0..31
    int ty = threadIdx.y;       // 0..7
    #pragma unroll
    for (int i = 0; i < 4; ++i)
        tile[ty + i*8][tx] = W[(size_t)(k0 + ty + i*8) * D_MODEL + n0 + tx];
    __syncthreads();
    unsigned short* dst = wt + (size_t)mat * D_MODEL * D_MODEL;
    #pragma unroll
    for (int i = 0; i < 4; ++i)
        dst[(size_t)(n0 + ty + i*8) * D_MODEL + k0 + tx] = f2bf(tile[tx][ty + i*8]);
}

// ---------------- QKV projection GEMM ----------------
// Q,K stored as [b][h][s][dk]; V stored TRANSPOSED as [b][h][dk][s].
#define BM 128
#define BN 128
#define BKK 64
__global__ __launch_bounds__(256) void qkv_gemm_kernel(const unsigned short* __restrict__ xb,
                                                       const unsigned short* __restrict__ wt,
                                                       const float* __restrict__ bq,
                                                       const float* __restrict__ bk,
                                                       const float* __restrict__ bv,
                                                       unsigned short* __restrict__ qkv) {
    __shared__ __align__(16) unsigned char sA[BM * BKK * 2];
    __shared__ __align__(16) unsigned char sB[BN * BKK * 2];

    int lin = blockIdx.y * 24 + blockIdx.x;          // 0..1535
    lin = (lin & 7) * 192 + (lin >> 3);              // bijective XCD-chunk swizzle
    int nb   = lin % 24;
    int mb   = lin / 24;
    int mat  = nb >> 3;
    int col0 = (nb & 7) * BN;
    int m0   = mb * BM;
    int t    = threadIdx.x;
    int lane = t & 63;
    int w    = t >> 6;

    const unsigned short* wmat = wt + (size_t)mat * D_MODEL * D_MODEL;
    const float* bias = (mat == 0) ? bq : (mat == 1) ? bk : bv;

    f32x4 acc[4][4];
    #pragma unroll
    for (int i = 0; i < 4; ++i)
        #pragma unroll
        for (int j = 0; j < 4; ++j)
            acc[i][j] = (f32x4)0.0f;

    int rA = (w >> 1) * 64;
    int rB = (w & 1) * 64;

    for (int ks = 0; ks < D_MODEL / BKK; ++ks) {
        int K0 = ks * BKK;
        #pragma unroll
        for (int i = 0; i < 4; ++i) {
            int c   = t + 256 * i;
            int row = c >> 3;
            int kc  = c & 7;
            int swz = kc ^ (row & 7);
            const unsigned short* ga = xb + (size_t)(m0 + row) * D_MODEL + K0 + swz * 8;
            __builtin_amdgcn_global_load_lds(
                (const __attribute__((address_space(1))) void*)ga,
                (__attribute__((address_space(3))) void*)(sA + c * 16), 16, 0, 0);
            const unsigned short* gb = wmat + (size_t)(col0 + row) * D_MODEL + K0 + swz * 8;
            __builtin_amdgcn_global_load_lds(
                (const __attribute__((address_space(1))) void*)gb,
                (__attribute__((address_space(3))) void*)(sB + c * 16), 16, 0, 0);
        }
        __syncthreads();

        #pragma unroll
        for (int kk = 0; kk < 2; ++kk) {
            bf16x8 af[4], bf[4];
            int kc = kk * 4 + (lane >> 4);
            #pragma unroll
            for (int mt = 0; mt < 4; ++mt) {
                int row = rA + mt * 16 + (lane & 15);
                int swz = kc ^ (row & 7);
                af[mt] = *(const bf16x8*)(sA + row * 128 + swz * 16);
            }
            #pragma unroll
            for (int nt = 0; nt < 4; ++nt) {
                int row = rB + nt * 16 + (lane & 15);
                int swz = kc ^ (row & 7);
                bf[nt] = *(const bf16x8*)(sB + row * 128 + swz * 16);
            }
            #pragma unroll
            for (int mt = 0; mt < 4; ++mt)
                #pragma unroll
                for (int nt = 0; nt < 4; ++nt)
                    acc[mt][nt] = __builtin_amdgcn_mfma_f32_16x16x32_bf16(
                        af[mt], bf[nt], acc[mt][nt], 0, 0, 0);
        }
        __syncthreads();
    }

    #pragma unroll
    for (int mt = 0; mt < 4; ++mt) {
        #pragma unroll
        for (int nt = 0; nt < 4; ++nt) {
            int gn = col0 + rB + nt * 16 + (lane & 15);
            float bval = bias[gn];
            #pragma unroll
            for (int r = 0; r < 4; ++r) {
                int gm = m0 + rA + mt * 16 + (lane >> 4) * 4 + r;
                float v = acc[mt][nt][r] + bval;
                if (mat == 0) v *= QSCALE;   // fold 1/sqrt(dk)*log2e into Q
                int b = gm >> 11, s = gm & 2047;
                int h = gn >> 6,  d = gn & 63;
                size_t idx;
                if (mat == 2)   // V transposed: [b][h][d][s]
                    idx = ((size_t)(b * NHEAD + h) * DK + d) * SEQ + s;
                else            // Q,K: [b][h][s][d]
                    idx = ((size_t)(b * NHEAD + h) * SEQ + s) * DK + d;
                qkv[(size_t)mat * MTOT * D_MODEL + idx] = f2bf(v);
            }
        }
    }
}

// ---------------- fused flash attention (swapped-QK^T, 32x32 MFMA) ----------------
// grid: (64 bh, 8 q-blocks of 256), 512 threads = 8 waves, each wave 32 q-rows.
// K: triple-buffered LDS (global_load_lds, XOR-swizzled src+read).
// V^T: DIRECT global->register A-frags (r4-verified pattern), issued at loop top.
// Cross-half reductions: __shfl_xor (r9/r11-proven; PLSWAP self-swap aliasing
// bug identified in r12 -- do NOT permlane-swap two copies of the same value).
// LDS: 3 x 8KB K buffers = 24KB.
#define CVTPK(dst, lo_, hi_) \
    asm("v_cvt_pk_bf16_f32 %0, %1, %2" : "=v"(dst) : "v"(lo_), "v"(hi_))
#define PLSWAP(x_, y_) \
    asm("v_permlane32_swap_b32 %0, %1" : "+v"(x_), "+v"(y_))
#define EXP2(dst, x_) \
    asm("v_exp_f32 %0, %1" : "=v"(dst) : "v"(x_))

// P^T B-frag from 8 per-lane P values (C-layout kv rows) via cvt_pk+permlane32_swap.
__device__ __forceinline__ bf16x8 make_pf(float p0, float p1, float p2, float p3,
                                          float p4, float p5, float p6, float p7) {
    unsigned a1, a2, b1, b2;
    CVTPK(a1, p0, p1); CVTPK(a2, p2, p3);
    CVTPK(b1, p4, p5); CVTPK(b2, p6, p7);
    PLSWAP(a1, b1); PLSWAP(a2, b2);
    u32x4 u = { a1, a2, b1, b2 };
    return __builtin_bit_cast(bf16x8, u);
}

// max of 16 via v_max3-fusable nests (T17)
__device__ __forceinline__ float vmax16(const f32x16& v) {
    float a = fmaxf(fmaxf(v[0],  v[1]),  v[2]);
    float b = fmaxf(fmaxf(v[3],  v[4]),  v[5]);
    float c = fmaxf(fmaxf(v[6],  v[7]),  v[8]);
    float d = fmaxf(fmaxf(v[9],  v[10]), v[11]);
    a = fmaxf(fmaxf(a, v[12]), v[13]);
    b = fmaxf(fmaxf(b, v[14]), v[15]);
    return fmaxf(fmaxf(a, b), fmaxf(c, d));
}

__global__ __launch_bounds__(512, 2) void attn_kernel(const unsigned short* __restrict__ qkv,
                                                      float* __restrict__ out) {
    __shared__ __align__(16) unsigned char lds[24576];

    int bh = blockIdx.x;      // b*16 + h
    int qb = blockIdx.y;      // 0..7
    int t = threadIdx.x;      // 0..511
    int lane = t & 63;
    int w = t >> 6;           // 0..7
    int hi = lane >> 5;       // 0/1
    int l31 = lane & 31;

    const unsigned short* Qb = qkv + (size_t)bh * SEQ * DK;
    const unsigned short* Kb = qkv + (size_t)MTOT * D_MODEL + (size_t)bh * SEQ * DK;
    const unsigned short* Vt = qkv + (size_t)2 * MTOT * D_MODEL + (size_t)bh * DK * SEQ; // [d][s]

    int qbase = qb * 256 + w * 32;

    // Q B-frags: col=q=lane&31, k=d=kd*16+hi*8+j   (Q pre-scaled by 1/8*log2e)
    bf16x8 aq[4];
    #pragma unroll
    for (int kd = 0; kd < 4; ++kd)
        aq[kd] = *(const bf16x8*)(Qb + (size_t)(qbase + l31) * DK + kd * 16 + hi * 8);

    f32x16 o0 = (f32x16)0.0f, o1 = (f32x16)0.0f;   // O^T[d][q], d-halves 0/1
    float mrun = -3e38f, lrun = 0.0f;

    // Stage K tile into buffer slot b_: per thread 1 chunk (16B).
#define STAGEK(tile_, b_) do {                                                         \
    int kv0_ = (tile_) * KVB;                                                          \
    int row_ = t >> 3, kc_ = t & 7;                                                    \
    int sw_ = (kc_ ^ (row_ & 7)) * 8;                                                  \
    __builtin_amdgcn_global_load_lds(                                                  \
        (const __attribute__((address_space(1))) void*)(Kb + (size_t)(kv0_ + row_) * DK + sw_), \
        (__attribute__((address_space(3))) void*)(lds + (b_) * 8192 + t * 16), 16, 0, 0);       \
} while (0)

    int swz7 = l31 & 7;
    int cofs0 = ((0 + hi) ^ swz7) << 4;
    int cofs1 = ((2 + hi) ^ swz7) << 4;
    int cofs2 = ((4 + hi) ^ swz7) << 4;
    int cofs3 = ((6 + hi) ^ swz7) << 4;

    // V^T per-lane base pointers (d-rows l31 and 32+l31), r4-verified pattern.
    const unsigned short* vrow0 = Vt + (size_t)l31 * SEQ + hi * 8;
    const unsigned short* vrow1 = Vt + (size_t)(32 + l31) * SEQ + hi * 8;

    // Prologue: stage K tiles 0 and 1; wait only tile 0.
    STAGEK(0, 0);
    STAGEK(1, 1);
    asm volatile("s_waitcnt vmcnt(1)" ::: "memory");
    __builtin_amdgcn_s_barrier();

    int b0 = 0, b1 = 1, b2 = 2;

    for (int kt = 0; kt < NT; ++kt) {
        int kv0 = kt * KVB;

        // ---- V^T A-frags for CURRENT tile: direct global loads, issued first ----
        bf16x8 av00 = *(const bf16x8*)(vrow0 + kv0);
        bf16x8 av01 = *(const bf16x8*)(vrow0 + kv0 + 16);
        bf16x8 av02 = *(const bf16x8*)(vrow0 + kv0 + 32);
        bf16x8 av03 = *(const bf16x8*)(vrow0 + kv0 + 48);
        bf16x8 av10 = *(const bf16x8*)(vrow1 + kv0);
        bf16x8 av11 = *(const bf16x8*)(vrow1 + kv0 + 16);
        bf16x8 av12 = *(const bf16x8*)(vrow1 + kv0 + 32);
        bf16x8 av13 = *(const bf16x8*)(vrow1 + kv0 + 48);

        // ---- K(t+2) stage (after V issues, so V-waits keep it in flight) ----
        if (kt + 2 < NT)
            STAGEK(kt + 2, b2);

        const unsigned char* kb = lds + b0 * 8192;
        const unsigned char* kr0 = kb + l31 * 128;
        const unsigned char* kr1 = kb + (32 + l31) * 128;

        // ---- S^T = K Q^T ----
        bf16x8 ak00 = *(const bf16x8*)(kr0 + cofs0);
        bf16x8 ak01 = *(const bf16x8*)(kr0 + cofs1);
        bf16x8 ak02 = *(const bf16x8*)(kr0 + cofs2);
        bf16x8 ak03 = *(const bf16x8*)(kr0 + cofs3);
        bf16x8 ak10 = *(const bf16x8*)(kr1 + cofs0);
        bf16x8 ak11 = *(const bf16x8*)(kr1 + cofs1);
        bf16x8 ak12 = *(const bf16x8*)(kr1 + cofs2);
        bf16x8 ak13 = *(const bf16x8*)(kr1 + cofs3);
        f32x16 sc0 = (f32x16)0.0f, sc1 = (f32x16)0.0f;
        __builtin_amdgcn_s_setprio(1);
        sc0 = __builtin_amdgcn_mfma_f32_32x32x16_bf16(ak00, aq[0], sc0, 0, 0, 0);
        sc1 = __builtin_amdgcn_mfma_f32_32x32x16_bf16(ak10, aq[0], sc1, 0, 0, 0);
        sc0 = __builtin_amdgcn_mfma_f32_32x32x16_bf16(ak01, aq[1], sc0, 0, 0, 0);
        sc1 = __builtin_amdgcn_mfma_f32_32x32x16_bf16(ak11, aq[1], sc1, 0, 0, 0);
        sc0 = __builtin_amdgcn_mfma_f32_32x32x16_bf16(ak02, aq[2], sc0, 0, 0, 0);
        sc1 = __builtin_amdgcn_mfma_f32_32x32x16_bf16(ak12, aq[2], sc1, 0, 0, 0);
        sc0 = __builtin_amdgcn_mfma_f32_32x32x16_bf16(ak03, aq[3], sc0, 0, 0, 0);
        sc1 = __builtin_amdgcn_mfma_f32_32x32x16_bf16(ak13, aq[3], sc1, 0, 0, 0);
        __builtin_amdgcn_s_setprio(0);

        // ---- online softmax (exp2 domain), defer-max THR=8 ----
        float mx = fmaxf(vmax16(sc0), vmax16(sc1));
        mx = fmaxf(mx, __shfl_xor(mx, 32));
        if (!__all(mx <= mrun + 8.0f)) {
            float mnew = fmaxf(mrun, mx);
            float al;  EXP2(al, mrun - mnew);
            lrun *= al;
            #pragma unroll
            for (int i = 0; i < 16; ++i) { o0[i] *= al; o1[i] *= al; }
            mrun = mnew;
        }
        #pragma unroll
        for (int i = 0; i < 16; ++i) { float p; EXP2(p, sc0[i] - mrun); sc0[i] = p; }
        #pragma unroll
        for (int i = 0; i < 16; ++i) { float p; EXP2(p, sc1[i] - mrun); sc1[i] = p; }
        float r0 = 0.f, r1 = 0.f, r2 = 0.f, r3 = 0.f;
        #pragma unroll
        for (int i = 0; i < 4; ++i) {
            r0 += sc0[i] + sc1[i];     r1 += sc0[4+i] + sc1[4+i];
            r2 += sc0[8+i] + sc1[8+i]; r3 += sc0[12+i] + sc1[12+i];
        }
        float rs = (r0 + r1) + (r2 + r3);
        rs += __shfl_xor(rs, 32);
        lrun += rs;

        // ---- P^T -> bf16 B-frags ----
        bf16x8 pf0 = make_pf(sc0[0], sc0[1], sc0[2],  sc0[3],  sc0[4],  sc0[5],  sc0[6],  sc0[7]);
        bf16x8 pf1 = make_pf(sc0[8], sc0[9], sc0[10], sc0[11], sc0[12], sc0[13], sc0[14], sc0[15]);
        bf16x8 pf2 = make_pf(sc1[0], sc1[1], sc1[2],  sc1[3],  sc1[4],  sc1[5],  sc1[6],  sc1[7]);
        bf16x8 pf3 = make_pf(sc1[8], sc1[9], sc1[10], sc1[11], sc1[12], sc1[13], sc1[14], sc1[15]);

        // ---- O^T += V^T P^T (compiler waits V loads here; retires K(t+1) too) ----
        __builtin_amdgcn_s_setprio(1);
        o0 = __builtin_amdgcn_mfma_f32_32x32x16_bf16(av00, pf0, o0, 0, 0, 0);
        o1 = __builtin_amdgcn_mfma_f32_32x32x16_bf16(av10, pf0, o1, 0, 0, 0);
        o0 = __builtin_amdgcn_mfma_f32_32x32x16_bf16(av01, pf1, o0, 0, 0, 0);
        o1 = __builtin_amdgcn_mfma_f32_32x32x16_bf16(av11, pf1, o1, 0, 0, 0);
        o0 = __builtin_amdgcn_mfma_f32_32x32x16_bf16(av02, pf2, o0, 0, 0, 0);
        o1 = __builtin_amdgcn_mfma_f32_32x32x16_bf16(av12, pf2, o1, 0, 0, 0);
        o0 = __builtin_amdgcn_mfma_f32_32x32x16_bf16(av03, pf3, o0, 0, 0, 0);
        o1 = __builtin_amdgcn_mfma_f32_32x32x16_bf16(av13, pf3, o1, 0, 0, 0);
        __builtin_amdgcn_s_setprio(0);

        // ---- ensure this tile's V consumed + K(t+1) landed (FIFO) before reuse ----
        asm volatile("s_waitcnt vmcnt(1)" ::: "memory");  // only K(t+2) may remain in flight
        __builtin_amdgcn_s_barrier();
        int tb = b0; b0 = b1; b1 = b2; b2 = tb;
    }
#undef STAGEK

    // ---- epilogue: direct f32x4 stores (C rows are 4-contiguous in d) ----
    int b = bh >> 4, h = bh & 15;
    float rl = 1.0f / lrun;
    float* dst = out + ((size_t)b * SEQ + qbase + l31) * D_MODEL + h * DK;
    #pragma unroll
    for (int g = 0; g < 4; ++g) {
        int d0 = 8 * g + 4 * hi;
        f32x4 v0 = { o0[4*g] * rl, o0[4*g+1] * rl, o0[4*g+2] * rl, o0[4*g+3] * rl };
        *(f32x4*)(dst + d0) = v0;
        f32x4 v1 = { o1[4*g] * rl, o1[4*g+1] * rl, o1[4*g+2] * rl, o1[4*g+3] * rl };
        *(f32x4*)(dst + 32 + d0) = v1;
    }
}

extern "C" void kernel_launch(void* const* d_in, const int* in_sizes, int n_in,
                              void* d_out, int out_size, void* d_ws, size_t ws_size,
                              hipStream_t stream) {
    const float* x  = (const float*)d_in[0];
    const float* Wq = (const float*)d_in[1];
    const float* bq = (const float*)d_in[2];
    const float* Wk = (const float*)d_in[3];
    const float* bk = (const float*)d_in[4];
    const float* Wv = (const float*)d_in[5];
    const float* bv = (const float*)d_in[6];
    float* out = (float*)d_out;

    unsigned short* xb  = (unsigned short*)d_ws;                       // 16 MB
    unsigned short* wt  = xb + (size_t)MTOT * D_MODEL;                 // 6 MB
    unsigned short* qkv = wt + (size_t)3 * D_MODEL * D_MODEL;          // 48 MB

    cvt_x_kernel<<<dim3(MTOT * D_MODEL / (256 * 8)), dim3(256), 0, stream>>>(x, xb);
    cvt_wt_kernel<<<dim3(32, 32, 3), dim3(32, 8), 0, stream>>>(Wq, Wk, Wv, wt);
    qkv_gemm_kernel<<<dim3(24, 64), dim3(256), 0, stream>>>(xb, wt, bq, bk, bv, qkv);
    attn_kernel<<<dim3(64, 8), dim3(512), 0, stream>>>(qkv, out);
}

// Round 14
// 196.486 us; speedup vs baseline: 1.4066x; 1.4066x over previous
//
#include <hip/hip_runtime.h>
#include <stdint.h>

#define D_MODEL 1024
#define NHEAD   16
#define DK      64
#define BATCH   4
#define SEQ     2048
#define MTOT    (BATCH*SEQ)   // 8192
#define KVB     64
#define NT      (SEQ/KVB)     // 32

typedef __attribute__((ext_vector_type(4)))  float  f32x4;
typedef __attribute__((ext_vector_type(16))) float  f32x16;
typedef __attribute__((ext_vector_type(8)))  __bf16 bf16x8;
typedef __attribute__((ext_vector_type(8)))  unsigned short u16x8;
typedef __attribute__((ext_vector_type(4)))  unsigned int u32x4;

// Q scale: 1/sqrt(dk) * log2(e)  (softmax computed in exp2 domain)
#define QSCALE 0.1803368801111244f

__device__ __forceinline__ unsigned short f2bf(float f) {
    unsigned u = __builtin_bit_cast(unsigned, f);
    u += 0x7fffu + ((u >> 16) & 1u);
    return (unsigned short)(u >> 16);
}

// ------- fused: x fp32->bf16 convert  +  W[k][n] -> W^T[n][k] bf16 -------
// grid: [0,4096) x-convert | [4096,7168) W-transpose (1024 blocks per matrix)
__global__ __launch_bounds__(256) void cvt_fused_kernel(const float* __restrict__ x,
                                                        const float* __restrict__ Wq,
                                                        const float* __restrict__ Wk,
                                                        const float* __restrict__ Wv,
                                                        unsigned short* __restrict__ xb,
                                                        unsigned short* __restrict__ wt) {
    __shared__ float tile[32][33];
    int bid = blockIdx.x;
    int tid = threadIdx.x;
    if (bid < 4096) {
        size_t i = ((size_t)bid * 256 + tid) * 8;
        f32x4 a = *(const f32x4*)(x + i);
        f32x4 b = *(const f32x4*)(x + i + 4);
        u16x8 o;
        o[0] = f2bf(a[0]); o[1] = f2bf(a[1]); o[2] = f2bf(a[2]); o[3] = f2bf(a[3]);
        o[4] = f2bf(b[0]); o[5] = f2bf(b[1]); o[6] = f2bf(b[2]); o[7] = f2bf(b[3]);
        *(u16x8*)(xb + i) = o;
        return;
    }
    int wid = bid - 4096;                 // 0..3071
    int mat = wid >> 10;                  // 0..2
    int r   = wid & 1023;
    int n0  = (r & 31) * 32;
    int k0  = (r >> 5) * 32;
    int tx  = tid & 31;                   // 0..31
    int ty  = tid >> 5;                   // 0..7
    const float* W = (mat == 0) ? Wq : (mat == 1) ? Wk : Wv;
    #pragma unroll
    for (int i = 0; i < 4; ++i)
        tile[ty + i*8][tx] = W[(size_t)(k0 + ty + i*8) * D_MODEL + n0 + tx];
    __syncthreads();
    unsigned short* dst = wt + (size_t)mat * D_MODEL * D_MODEL;
    #pragma unroll
    for (int i = 0; i < 4; ++i)
        dst[(size_t)(n0 + ty + i*8) * D_MODEL + k0 + tx] = f2bf(tile[tx][ty + i*8]);
}

// ---------------- QKV projection GEMM ----------------
// Q,K stored as [b][h][s][dk]; V stored TRANSPOSED as [b][h][dk][s].
#define BM 128
#define BN 128
#define BKK 64
__global__ __launch_bounds__(256) void qkv_gemm_kernel(const unsigned short* __restrict__ xb,
                                                       const unsigned short* __restrict__ wt,
                                                       const float* __restrict__ bq,
                                                       const float* __restrict__ bk,
                                                       const float* __restrict__ bv,
                                                       unsigned short* __restrict__ qkv) {
    __shared__ __align__(16) unsigned char sA[BM * BKK * 2];
    __shared__ __align__(16) unsigned char sB[BN * BKK * 2];

    int lin = blockIdx.y * 24 + blockIdx.x;          // 0..1535
    lin = (lin & 7) * 192 + (lin >> 3);              // bijective XCD-chunk swizzle
    int nb   = lin % 24;
    int mb   = lin / 24;
    int mat  = nb >> 3;
    int col0 = (nb & 7) * BN;
    int m0   = mb * BM;
    int t    = threadIdx.x;
    int lane = t & 63;
    int w    = t >> 6;

    const unsigned short* wmat = wt + (size_t)mat * D_MODEL * D_MODEL;
    const float* bias = (mat == 0) ? bq : (mat == 1) ? bk : bv;

    f32x4 acc[4][4];
    #pragma unroll
    for (int i = 0; i < 4; ++i)
        #pragma unroll
        for (int j = 0; j < 4; ++j)
            acc[i][j] = (f32x4)0.0f;

    int rA = (w >> 1) * 64;
    int rB = (w & 1) * 64;

    for (int ks = 0; ks < D_MODEL / BKK; ++ks) {
        int K0 = ks * BKK;
        #pragma unroll
        for (int i = 0; i < 4; ++i) {
            int c   = t + 256 * i;
            int row = c >> 3;
            int kc  = c & 7;
            int swz = kc ^ (row & 7);
            const unsigned short* ga = xb + (size_t)(m0 + row) * D_MODEL + K0 + swz * 8;
            __builtin_amdgcn_global_load_lds(
                (const __attribute__((address_space(1))) void*)ga,
                (__attribute__((address_space(3))) void*)(sA + c * 16), 16, 0, 0);
            const unsigned short* gb = wmat + (size_t)(col0 + row) * D_MODEL + K0 + swz * 8;
            __builtin_amdgcn_global_load_lds(
                (const __attribute__((address_space(1))) void*)gb,
                (__attribute__((address_space(3))) void*)(sB + c * 16), 16, 0, 0);
        }
        __syncthreads();

        #pragma unroll
        for (int kk = 0; kk < 2; ++kk) {
            bf16x8 af[4], bf[4];
            int kc = kk * 4 + (lane >> 4);
            #pragma unroll
            for (int mt = 0; mt < 4; ++mt) {
                int row = rA + mt * 16 + (lane & 15);
                int swz = kc ^ (row & 7);
                af[mt] = *(const bf16x8*)(sA + row * 128 + swz * 16);
            }
            #pragma unroll
            for (int nt = 0; nt < 4; ++nt) {
                int row = rB + nt * 16 + (lane & 15);
                int swz = kc ^ (row & 7);
                bf[nt] = *(const bf16x8*)(sB + row * 128 + swz * 16);
            }
            #pragma unroll
            for (int mt = 0; mt < 4; ++mt)
                #pragma unroll
                for (int nt = 0; nt < 4; ++nt)
                    acc[mt][nt] = __builtin_amdgcn_mfma_f32_16x16x32_bf16(
                        af[mt], bf[nt], acc[mt][nt], 0, 0, 0);
        }
        __syncthreads();
    }

    #pragma unroll
    for (int mt = 0; mt < 4; ++mt) {
        #pragma unroll
        for (int nt = 0; nt < 4; ++nt) {
            int gn = col0 + rB + nt * 16 + (lane & 15);
            float bval = bias[gn];
            #pragma unroll
            for (int r = 0; r < 4; ++r) {
                int gm = m0 + rA + mt * 16 + (lane >> 4) * 4 + r;
                float v = acc[mt][nt][r] + bval;
                if (mat == 0) v *= QSCALE;   // fold 1/sqrt(dk)*log2e into Q
                int b = gm >> 11, s = gm & 2047;
                int h = gn >> 6,  d = gn & 63;
                size_t idx;
                if (mat == 2)   // V transposed: [b][h][d][s]
                    idx = ((size_t)(b * NHEAD + h) * DK + d) * SEQ + s;
                else            // Q,K: [b][h][s][d]
                    idx = ((size_t)(b * NHEAD + h) * SEQ + s) * DK + d;
                qkv[(size_t)mat * MTOT * D_MODEL + idx] = f2bf(v);
            }
        }
    }
}

// ---------------- fused flash attention (swapped-QK^T, 32x32 MFMA, LDS-staged) ----------------
// grid: (64 bh, 8 q-blocks of 256), 512 threads = 8 waves, each wave 32 q-rows.
// r11 structure (verified 106us): triple-buffered K/V in LDS, counted vmcnt(2),
// defer-max softmax, cvt_pk+permlane P-frags, shfl cross-half reductions.
// LDS: K bufs [0,24576) = 3 x 8K | V^T bufs [24576,49152) = 3 x 8K
#define CVTPK(dst, lo_, hi_) \
    asm("v_cvt_pk_bf16_f32 %0, %1, %2" : "=v"(dst) : "v"(lo_), "v"(hi_))
#define PLSWAP(x_, y_) \
    asm("v_permlane32_swap_b32 %0, %1" : "+v"(x_), "+v"(y_))
#define EXP2(dst, x_) \
    asm("v_exp_f32 %0, %1" : "=v"(dst) : "v"(x_))

// P^T B-frag from 8 per-lane P values (C-layout kv rows) via cvt_pk+permlane32_swap.
__device__ __forceinline__ bf16x8 make_pf(float p0, float p1, float p2, float p3,
                                          float p4, float p5, float p6, float p7) {
    unsigned a1, a2, b1, b2;
    CVTPK(a1, p0, p1); CVTPK(a2, p2, p3);
    CVTPK(b1, p4, p5); CVTPK(b2, p6, p7);
    PLSWAP(a1, b1); PLSWAP(a2, b2);
    u32x4 u = { a1, a2, b1, b2 };
    return __builtin_bit_cast(bf16x8, u);
}

// max of 16 via v_max3-fusable nests (T17)
__device__ __forceinline__ float vmax16(const f32x16& v) {
    float a = fmaxf(fmaxf(v[0],  v[1]),  v[2]);
    float b = fmaxf(fmaxf(v[3],  v[4]),  v[5]);
    float c = fmaxf(fmaxf(v[6],  v[7]),  v[8]);
    float d = fmaxf(fmaxf(v[9],  v[10]), v[11]);
    a = fmaxf(fmaxf(a, v[12]), v[13]);
    b = fmaxf(fmaxf(b, v[14]), v[15]);
    return fmaxf(fmaxf(a, b), fmaxf(c, d));
}

__global__ __launch_bounds__(512, 2) void attn_kernel(const unsigned short* __restrict__ qkv,
                                                      float* __restrict__ out) {
    __shared__ __align__(16) unsigned char lds[49152];

    int bh = blockIdx.x;      // b*16 + h
    int qb = blockIdx.y;      // 0..7
    int t = threadIdx.x;      // 0..511
    int lane = t & 63;
    int w = t >> 6;           // 0..7
    int hi = lane >> 5;       // 0/1
    int l31 = lane & 31;

    const unsigned short* Qb = qkv + (size_t)bh * SEQ * DK;
    const unsigned short* Kb = qkv + (size_t)MTOT * D_MODEL + (size_t)bh * SEQ * DK;
    const unsigned short* Vt = qkv + (size_t)2 * MTOT * D_MODEL + (size_t)bh * DK * SEQ; // [d][s]

    int qbase = qb * 256 + w * 32;

    // Q B-frags: col=q=lane&31, k=d=kd*16+hi*8+j   (Q pre-scaled by 1/8*log2e)
    bf16x8 aq[4];
    #pragma unroll
    for (int kd = 0; kd < 4; ++kd)
        aq[kd] = *(const bf16x8*)(Qb + (size_t)(qbase + l31) * DK + kd * 16 + hi * 8);

    f32x16 o0 = (f32x16)0.0f, o1 = (f32x16)0.0f;   // O^T[d][q], d-halves 0/1
    float mrun = -3e38f, lrun = 0.0f;

    // Stage tile into buffer slot b_: per thread 1 K-chunk + 1 V-chunk (16B each).
#define STAGE(tile_, b_) do {                                                          \
    int kv0_ = (tile_) * KVB;                                                          \
    int row_ = t >> 3, kc_ = t & 7;                                                    \
    int sw_ = (kc_ ^ (row_ & 7)) * 8;                                                  \
    __builtin_amdgcn_global_load_lds(                                                  \
        (const __attribute__((address_space(1))) void*)(Kb + (size_t)(kv0_ + row_) * DK + sw_), \
        (__attribute__((address_space(3))) void*)(lds + (b_) * 8192 + t * 16), 16, 0, 0);       \
    __builtin_amdgcn_global_load_lds(                                                  \
        (const __attribute__((address_space(1))) void*)(Vt + (size_t)row_ * SEQ + kv0_ + sw_),  \
        (__attribute__((address_space(3))) void*)(lds + 24576 + (b_) * 8192 + t * 16), 16, 0, 0); \
} while (0)

    int swz7 = l31 & 7;
    int cofs0 = ((0 + hi) ^ swz7) << 4;
    int cofs1 = ((2 + hi) ^ swz7) << 4;
    int cofs2 = ((4 + hi) ^ swz7) << 4;
    int cofs3 = ((6 + hi) ^ swz7) << 4;

    // Prologue: stage tiles 0 and 1; wait only tile 0 (keep tile 1 in flight).
    STAGE(0, 0);
    STAGE(1, 1);
    asm volatile("s_waitcnt vmcnt(2)" ::: "memory");
    __builtin_amdgcn_s_barrier();

    int b0 = 0, b1 = 1, b2 = 2;   // current / next / stage-target buffer slots

    for (int kt = 0; kt < NT; ++kt) {
        if (kt + 2 < NT)
            STAGE(kt + 2, b2);

        const unsigned char* kb = lds + b0 * 8192;
        const unsigned char* vb = lds + 24576 + b0 * 8192;
        const unsigned char* kr0 = kb + l31 * 128;
        const unsigned char* kr1 = kb + (32 + l31) * 128;
        const unsigned char* vr0 = vb + l31 * 128;
        const unsigned char* vr1 = vb + (32 + l31) * 128;

        // ---- S^T = K Q^T ----
        bf16x8 ak00 = *(const bf16x8*)(kr0 + cofs0);
        bf16x8 ak01 = *(const bf16x8*)(kr0 + cofs1);
        bf16x8 ak02 = *(const bf16x8*)(kr0 + cofs2);
        bf16x8 ak03 = *(const bf16x8*)(kr0 + cofs3);
        bf16x8 ak10 = *(const bf16x8*)(kr1 + cofs0);
        bf16x8 ak11 = *(const bf16x8*)(kr1 + cofs1);
        bf16x8 ak12 = *(const bf16x8*)(kr1 + cofs2);
        bf16x8 ak13 = *(const bf16x8*)(kr1 + cofs3);
        f32x16 sc0 = (f32x16)0.0f, sc1 = (f32x16)0.0f;
        __builtin_amdgcn_s_setprio(1);
        sc0 = __builtin_amdgcn_mfma_f32_32x32x16_bf16(ak00, aq[0], sc0, 0, 0, 0);
        sc1 = __builtin_amdgcn_mfma_f32_32x32x16_bf16(ak10, aq[0], sc1, 0, 0, 0);
        sc0 = __builtin_amdgcn_mfma_f32_32x32x16_bf16(ak01, aq[1], sc0, 0, 0, 0);
        sc1 = __builtin_amdgcn_mfma_f32_32x32x16_bf16(ak11, aq[1], sc1, 0, 0, 0);
        sc0 = __builtin_amdgcn_mfma_f32_32x32x16_bf16(ak02, aq[2], sc0, 0, 0, 0);
        sc1 = __builtin_amdgcn_mfma_f32_32x32x16_bf16(ak12, aq[2], sc1, 0, 0, 0);
        sc0 = __builtin_amdgcn_mfma_f32_32x32x16_bf16(ak03, aq[3], sc0, 0, 0, 0);
        sc1 = __builtin_amdgcn_mfma_f32_32x32x16_bf16(ak13, aq[3], sc1, 0, 0, 0);
        __builtin_amdgcn_s_setprio(0);

        // ---- V^T frags issued now; latency hides under softmax VALU ----
        bf16x8 av00 = *(const bf16x8*)(vr0 + cofs0);
        bf16x8 av01 = *(const bf16x8*)(vr0 + cofs1);
        bf16x8 av02 = *(const bf16x8*)(vr0 + cofs2);
        bf16x8 av03 = *(const bf16x8*)(vr0 + cofs3);
        bf16x8 av10 = *(const bf16x8*)(vr1 + cofs0);
        bf16x8 av11 = *(const bf16x8*)(vr1 + cofs1);
        bf16x8 av12 = *(const bf16x8*)(vr1 + cofs2);
        bf16x8 av13 = *(const bf16x8*)(vr1 + cofs3);

        // ---- online softmax (exp2 domain), defer-max THR=8 ----
        float mx = fmaxf(vmax16(sc0), vmax16(sc1));
        mx = fmaxf(mx, __shfl_xor(mx, 32));
        if (!__all(mx <= mrun + 8.0f)) {
            float mnew = fmaxf(mrun, mx);
            float al;  EXP2(al, mrun - mnew);
            lrun *= al;
            #pragma unroll
            for (int i = 0; i < 16; ++i) { o0[i] *= al; o1[i] *= al; }
            mrun = mnew;
        }
        #pragma unroll
        for (int i = 0; i < 16; ++i) { float p; EXP2(p, sc0[i] - mrun); sc0[i] = p; }
        #pragma unroll
        for (int i = 0; i < 16; ++i) { float p; EXP2(p, sc1[i] - mrun); sc1[i] = p; }
        float r0 = 0.f, r1 = 0.f, r2 = 0.f, r3 = 0.f;
        #pragma unroll
        for (int i = 0; i < 4; ++i) {
            r0 += sc0[i] + sc1[i];     r1 += sc0[4+i] + sc1[4+i];
            r2 += sc0[8+i] + sc1[8+i]; r3 += sc0[12+i] + sc1[12+i];
        }
        float rs = (r0 + r1) + (r2 + r3);
        rs += __shfl_xor(rs, 32);
        lrun += rs;

        // ---- P^T -> bf16 B-frags ----
        bf16x8 pf0 = make_pf(sc0[0], sc0[1], sc0[2],  sc0[3],  sc0[4],  sc0[5],  sc0[6],  sc0[7]);
        bf16x8 pf1 = make_pf(sc0[8], sc0[9], sc0[10], sc0[11], sc0[12], sc0[13], sc0[14], sc0[15]);
        bf16x8 pf2 = make_pf(sc1[0], sc1[1], sc1[2],  sc1[3],  sc1[4],  sc1[5],  sc1[6],  sc1[7]);
        bf16x8 pf3 = make_pf(sc1[8], sc1[9], sc1[10], sc1[11], sc1[12], sc1[13], sc1[14], sc1[15]);

        // ---- O^T += V^T P^T ----
        __builtin_amdgcn_s_setprio(1);
        o0 = __builtin_amdgcn_mfma_f32_32x32x16_bf16(av00, pf0, o0, 0, 0, 0);
        o1 = __builtin_amdgcn_mfma_f32_32x32x16_bf16(av10, pf0, o1, 0, 0, 0);
        o0 = __builtin_amdgcn_mfma_f32_32x32x16_bf16(av01, pf1, o0, 0, 0, 0);
        o1 = __builtin_amdgcn_mfma_f32_32x32x16_bf16(av11, pf1, o1, 0, 0, 0);
        o0 = __builtin_amdgcn_mfma_f32_32x32x16_bf16(av02, pf2, o0, 0, 0, 0);
        o1 = __builtin_amdgcn_mfma_f32_32x32x16_bf16(av12, pf2, o1, 0, 0, 0);
        o0 = __builtin_amdgcn_mfma_f32_32x32x16_bf16(av03, pf3, o0, 0, 0, 0);
        o1 = __builtin_amdgcn_mfma_f32_32x32x16_bf16(av13, pf3, o1, 0, 0, 0);
        __builtin_amdgcn_s_setprio(0);

        // ---- counted-vmcnt barrier: keep this iter's stage in flight ----
        if (kt + 2 < NT) {
            asm volatile("s_waitcnt vmcnt(2)" ::: "memory");   // retire next tile's loads
            __builtin_amdgcn_s_barrier();
        } else if (kt + 1 < NT) {
            asm volatile("s_waitcnt vmcnt(0)" ::: "memory");   // drain for last tile
            __builtin_amdgcn_s_barrier();
        }
        int tb = b0; b0 = b1; b1 = b2; b2 = tb;
    }
#undef STAGE

    // ---- epilogue: direct f32x4 stores (C rows are 4-contiguous in d) ----
    int b = bh >> 4, h = bh & 15;
    float rl = 1.0f / lrun;
    float* dst = out + ((size_t)b * SEQ + qbase + l31) * D_MODEL + h * DK;
    #pragma unroll
    for (int g = 0; g < 4; ++g) {
        int d0 = 8 * g + 4 * hi;
        f32x4 v0 = { o0[4*g] * rl, o0[4*g+1] * rl, o0[4*g+2] * rl, o0[4*g+3] * rl };
        *(f32x4*)(dst + d0) = v0;
        f32x4 v1 = { o1[4*g] * rl, o1[4*g+1] * rl, o1[4*g+2] * rl, o1[4*g+3] * rl };
        *(f32x4*)(dst + 32 + d0) = v1;
    }
}

extern "C" void kernel_launch(void* const* d_in, const int* in_sizes, int n_in,
                              void* d_out, int out_size, void* d_ws, size_t ws_size,
                              hipStream_t stream) {
    const float* x  = (const float*)d_in[0];
    const float* Wq = (const float*)d_in[1];
    const float* bq = (const float*)d_in[2];
    const float* Wk = (const float*)d_in[3];
    const float* bk = (const float*)d_in[4];
    const float* Wv = (const float*)d_in[5];
    const float* bv = (const float*)d_in[6];
    float* out = (float*)d_out;

    unsigned short* xb  = (unsigned short*)d_ws;                       // 16 MB
    unsigned short* wt  = xb + (size_t)MTOT * D_MODEL;                 // 6 MB
    unsigned short* qkv = wt + (size_t)3 * D_MODEL * D_MODEL;          // 48 MB

    cvt_fused_kernel<<<dim3(7168), dim3(256), 0, stream>>>(x, Wq, Wk, Wv, xb, wt);
    qkv_gemm_kernel<<<dim3(24, 64), dim3(256), 0, stream>>>(xb, wt, bq, bk, bv, qkv);
    attn_kernel<<<dim3(64, 8), dim3(512), 0, stream>>>(qkv, out);
}

// Round 15
// 188.830 us; speedup vs baseline: 1.4636x; 1.0405x over previous
//
#include <hip/hip_runtime.h>
#include <stdint.h>

#define D_MODEL 1024
#define NHEAD   16
#define DK      64
#define BATCH   4
#define SEQ     2048
#define MTOT    (BATCH*SEQ)   // 8192
#define KVB     64
#define NT      (SEQ/KVB)     // 32

typedef __attribute__((ext_vector_type(4)))  float  f32x4;
typedef __attribute__((ext_vector_type(16))) float  f32x16;
typedef __attribute__((ext_vector_type(8)))  __bf16 bf16x8;
typedef __attribute__((ext_vector_type(8)))  unsigned short u16x8;
typedef __attribute__((ext_vector_type(4)))  unsigned int u32x4;

// Q scale: 1/sqrt(dk) * log2(e)  (softmax computed in exp2 domain)
#define QSCALE 0.1803368801111244f

__device__ __forceinline__ unsigned short f2bf(float f) {
    unsigned u = __builtin_bit_cast(unsigned, f);
    u += 0x7fffu + ((u >> 16) & 1u);
    return (unsigned short)(u >> 16);
}

// ------- fused: x fp32->bf16 convert  +  W[k][n] -> W^T[n][k] bf16 -------
__global__ __launch_bounds__(256) void cvt_fused_kernel(const float* __restrict__ x,
                                                        const float* __restrict__ Wq,
                                                        const float* __restrict__ Wk,
                                                        const float* __restrict__ Wv,
                                                        unsigned short* __restrict__ xb,
                                                        unsigned short* __restrict__ wt) {
    __shared__ float tile[32][33];
    int bid = blockIdx.x;
    int tid = threadIdx.x;
    if (bid < 4096) {
        size_t i = ((size_t)bid * 256 + tid) * 8;
        f32x4 a = *(const f32x4*)(x + i);
        f32x4 b = *(const f32x4*)(x + i + 4);
        u16x8 o;
        o[0] = f2bf(a[0]); o[1] = f2bf(a[1]); o[2] = f2bf(a[2]); o[3] = f2bf(a[3]);
        o[4] = f2bf(b[0]); o[5] = f2bf(b[1]); o[6] = f2bf(b[2]); o[7] = f2bf(b[3]);
        *(u16x8*)(xb + i) = o;
        return;
    }
    int wid = bid - 4096;                 // 0..3071
    int mat = wid >> 10;                  // 0..2
    int r   = wid & 1023;
    int n0  = (r & 31) * 32;
    int k0  = (r >> 5) * 32;
    int tx  = tid & 31;                   // 0..31
    int ty  = tid >> 5;                   // 0..7
    const float* W = (mat == 0) ? Wq : (mat == 1) ? Wk : Wv;
    #pragma unroll
    for (int i = 0; i < 4; ++i)
        tile[ty + i*8][tx] = W[(size_t)(k0 + ty + i*8) * D_MODEL + n0 + tx];
    __syncthreads();
    unsigned short* dst = wt + (size_t)mat * D_MODEL * D_MODEL;
    #pragma unroll
    for (int i = 0; i < 4; ++i)
        dst[(size_t)(n0 + ty + i*8) * D_MODEL + k0 + tx] = f2bf(tile[tx][ty + i*8]);
}

// ---------------- QKV projection GEMM ----------------
// Q,K stored as [b][h][s][dk]; V stored TRANSPOSED as [b][h][dk][s].
#define BM 128
#define BN 128
#define BKK 64
__global__ __launch_bounds__(256) void qkv_gemm_kernel(const unsigned short* __restrict__ xb,
                                                       const unsigned short* __restrict__ wt,
                                                       const float* __restrict__ bq,
                                                       const float* __restrict__ bk,
                                                       const float* __restrict__ bv,
                                                       unsigned short* __restrict__ qkv) {
    __shared__ __align__(16) unsigned char sA[BM * BKK * 2];
    __shared__ __align__(16) unsigned char sB[BN * BKK * 2];

    int lin = blockIdx.y * 24 + blockIdx.x;          // 0..1535
    lin = (lin & 7) * 192 + (lin >> 3);              // bijective XCD-chunk swizzle
    int nb   = lin % 24;
    int mb   = lin / 24;
    int mat  = nb >> 3;
    int col0 = (nb & 7) * BN;
    int m0   = mb * BM;
    int t    = threadIdx.x;
    int lane = t & 63;
    int w    = t >> 6;

    const unsigned short* wmat = wt + (size_t)mat * D_MODEL * D_MODEL;
    const float* bias = (mat == 0) ? bq : (mat == 1) ? bk : bv;

    f32x4 acc[4][4];
    #pragma unroll
    for (int i = 0; i < 4; ++i)
        #pragma unroll
        for (int j = 0; j < 4; ++j)
            acc[i][j] = (f32x4)0.0f;

    int rA = (w >> 1) * 64;
    int rB = (w & 1) * 64;

    for (int ks = 0; ks < D_MODEL / BKK; ++ks) {
        int K0 = ks * BKK;
        #pragma unroll
        for (int i = 0; i < 4; ++i) {
            int c   = t + 256 * i;
            int row = c >> 3;
            int kc  = c & 7;
            int swz = kc ^ (row & 7);
            const unsigned short* ga = xb + (size_t)(m0 + row) * D_MODEL + K0 + swz * 8;
            __builtin_amdgcn_global_load_lds(
                (const __attribute__((address_space(1))) void*)ga,
                (__attribute__((address_space(3))) void*)(sA + c * 16), 16, 0, 0);
            const unsigned short* gb = wmat + (size_t)(col0 + row) * D_MODEL + K0 + swz * 8;
            __builtin_amdgcn_global_load_lds(
                (const __attribute__((address_space(1))) void*)gb,
                (__attribute__((address_space(3))) void*)(sB + c * 16), 16, 0, 0);
        }
        __syncthreads();

        #pragma unroll
        for (int kk = 0; kk < 2; ++kk) {
            bf16x8 af[4], bf[4];
            int kc = kk * 4 + (lane >> 4);
            #pragma unroll
            for (int mt = 0; mt < 4; ++mt) {
                int row = rA + mt * 16 + (lane & 15);
                int swz = kc ^ (row & 7);
                af[mt] = *(const bf16x8*)(sA + row * 128 + swz * 16);
            }
            #pragma unroll
            for (int nt = 0; nt < 4; ++nt) {
                int row = rB + nt * 16 + (lane & 15);
                int swz = kc ^ (row & 7);
                bf[nt] = *(const bf16x8*)(sB + row * 128 + swz * 16);
            }
            #pragma unroll
            for (int mt = 0; mt < 4; ++mt)
                #pragma unroll
                for (int nt = 0; nt < 4; ++nt)
                    acc[mt][nt] = __builtin_amdgcn_mfma_f32_16x16x32_bf16(
                        af[mt], bf[nt], acc[mt][nt], 0, 0, 0);
        }
        __syncthreads();
    }

    #pragma unroll
    for (int mt = 0; mt < 4; ++mt) {
        #pragma unroll
        for (int nt = 0; nt < 4; ++nt) {
            int gn = col0 + rB + nt * 16 + (lane & 15);
            float bval = bias[gn];
            #pragma unroll
            for (int r = 0; r < 4; ++r) {
                int gm = m0 + rA + mt * 16 + (lane >> 4) * 4 + r;
                float v = acc[mt][nt][r] + bval;
                if (mat == 0) v *= QSCALE;   // fold 1/sqrt(dk)*log2e into Q
                int b = gm >> 11, s = gm & 2047;
                int h = gn >> 6,  d = gn & 63;
                size_t idx;
                if (mat == 2)   // V transposed: [b][h][d][s]
                    idx = ((size_t)(b * NHEAD + h) * DK + d) * SEQ + s;
                else            // Q,K: [b][h][s][d]
                    idx = ((size_t)(b * NHEAD + h) * SEQ + s) * DK + d;
                qkv[(size_t)mat * MTOT * D_MODEL + idx] = f2bf(v);
            }
        }
    }
}

// ---------------- fused flash attention (swapped-QK^T, 32x32 MFMA, LDS-staged) ----------------
// grid: (64 bh, 8 q-blocks of 256), 256 threads = 4 waves, each wave 64 q-rows
// (two 32-row subtiles A/B sharing every K/V LDS fragment -> LDS traffic per
// unit work halved vs the 8-wave/32-row version). Triple-buffered K/V in LDS,
// counted vmcnt(2); r14-verified math per subtile.
// LDS: K bufs [0,24576) = 3 x 8K | V^T bufs [24576,49152) = 3 x 8K
#define CVTPK(dst, lo_, hi_) \
    asm("v_cvt_pk_bf16_f32 %0, %1, %2" : "=v"(dst) : "v"(lo_), "v"(hi_))
#define PLSWAP(x_, y_) \
    asm("v_permlane32_swap_b32 %0, %1" : "+v"(x_), "+v"(y_))
#define EXP2(dst, x_) \
    asm("v_exp_f32 %0, %1" : "=v"(dst) : "v"(x_))

// P^T B-frag from 8 per-lane P values (C-layout kv rows) via cvt_pk+permlane32_swap.
__device__ __forceinline__ bf16x8 make_pf(float p0, float p1, float p2, float p3,
                                          float p4, float p5, float p6, float p7) {
    unsigned a1, a2, b1, b2;
    CVTPK(a1, p0, p1); CVTPK(a2, p2, p3);
    CVTPK(b1, p4, p5); CVTPK(b2, p6, p7);
    PLSWAP(a1, b1); PLSWAP(a2, b2);
    u32x4 u = { a1, a2, b1, b2 };
    return __builtin_bit_cast(bf16x8, u);
}

// max of 16 via v_max3-fusable nests (T17)
__device__ __forceinline__ float vmax16(const f32x16& v) {
    float a = fmaxf(fmaxf(v[0],  v[1]),  v[2]);
    float b = fmaxf(fmaxf(v[3],  v[4]),  v[5]);
    float c = fmaxf(fmaxf(v[6],  v[7]),  v[8]);
    float d = fmaxf(fmaxf(v[9],  v[10]), v[11]);
    a = fmaxf(fmaxf(a, v[12]), v[13]);
    b = fmaxf(fmaxf(b, v[14]), v[15]);
    return fmaxf(fmaxf(a, b), fmaxf(c, d));
}

__global__ __launch_bounds__(256, 2) void attn_kernel(const unsigned short* __restrict__ qkv,
                                                      float* __restrict__ out) {
    __shared__ __align__(16) unsigned char lds[49152];

    int bh = blockIdx.x;      // b*16 + h
    int qb = blockIdx.y;      // 0..7
    int t = threadIdx.x;      // 0..255
    int lane = t & 63;
    int w = t >> 6;           // 0..3
    int hi = lane >> 5;       // 0/1
    int l31 = lane & 31;

    const unsigned short* Qb = qkv + (size_t)bh * SEQ * DK;
    const unsigned short* Kb = qkv + (size_t)MTOT * D_MODEL + (size_t)bh * SEQ * DK;
    const unsigned short* Vt = qkv + (size_t)2 * MTOT * D_MODEL + (size_t)bh * DK * SEQ; // [d][s]

    int qbase0 = qb * 256 + w * 64;       // subtile A
    int qbase1 = qbase0 + 32;             // subtile B

    // Q B-frags for both subtiles: col=q=lane&31, k=d=kd*16+hi*8+j
    bf16x8 aqA[4], aqB[4];
    #pragma unroll
    for (int kd = 0; kd < 4; ++kd) {
        aqA[kd] = *(const bf16x8*)(Qb + (size_t)(qbase0 + l31) * DK + kd * 16 + hi * 8);
        aqB[kd] = *(const bf16x8*)(Qb + (size_t)(qbase1 + l31) * DK + kd * 16 + hi * 8);
    }

    f32x16 oA0 = (f32x16)0.0f, oA1 = (f32x16)0.0f;
    f32x16 oB0 = (f32x16)0.0f, oB1 = (f32x16)0.0f;
    float mrunA = -3e38f, lrunA = 0.0f;
    float mrunB = -3e38f, lrunB = 0.0f;

    // Stage tile into buffer slot b_: 256 threads x 2 chunks (K and V each 8KB).
#define STAGE(tile_, b_) do {                                                          \
    int kv0_ = (tile_) * KVB;                                                          \
    _Pragma("unroll")                                                                  \
    for (int i_ = 0; i_ < 2; ++i_) {                                                   \
        int c_ = t + 256 * i_;                                                         \
        int row_ = c_ >> 3, kc_ = c_ & 7;                                              \
        int sw_ = (kc_ ^ (row_ & 7)) * 8;                                              \
        __builtin_amdgcn_global_load_lds(                                              \
            (const __attribute__((address_space(1))) void*)(Kb + (size_t)(kv0_ + row_) * DK + sw_), \
            (__attribute__((address_space(3))) void*)(lds + (b_) * 8192 + c_ * 16), 16, 0, 0);      \
        __builtin_amdgcn_global_load_lds(                                              \
            (const __attribute__((address_space(1))) void*)(Vt + (size_t)row_ * SEQ + kv0_ + sw_),  \
            (__attribute__((address_space(3))) void*)(lds + 24576 + (b_) * 8192 + c_ * 16), 16, 0, 0); \
    }                                                                                  \
} while (0)

    int swz7 = l31 & 7;
    int cofs0 = ((0 + hi) ^ swz7) << 4;
    int cofs1 = ((2 + hi) ^ swz7) << 4;
    int cofs2 = ((4 + hi) ^ swz7) << 4;
    int cofs3 = ((6 + hi) ^ swz7) << 4;

    // Prologue: stage tiles 0 and 1; wait only tile 0 (4 loads/thread in flight -> 2 remain).
    STAGE(0, 0);
    STAGE(1, 1);
    asm volatile("s_waitcnt vmcnt(4)" ::: "memory");
    __builtin_amdgcn_s_barrier();

    int b0 = 0, b1 = 1, b2 = 2;

    for (int kt = 0; kt < NT; ++kt) {
        if (kt + 2 < NT)
            STAGE(kt + 2, b2);

        const unsigned char* kb = lds + b0 * 8192;
        const unsigned char* vb = lds + 24576 + b0 * 8192;
        const unsigned char* kr0 = kb + l31 * 128;
        const unsigned char* kr1 = kb + (32 + l31) * 128;
        const unsigned char* vr0 = vb + l31 * 128;
        const unsigned char* vr1 = vb + (32 + l31) * 128;

        // ---- K frags (shared by both subtiles) ----
        bf16x8 ak00 = *(const bf16x8*)(kr0 + cofs0);
        bf16x8 ak01 = *(const bf16x8*)(kr0 + cofs1);
        bf16x8 ak02 = *(const bf16x8*)(kr0 + cofs2);
        bf16x8 ak03 = *(const bf16x8*)(kr0 + cofs3);
        bf16x8 ak10 = *(const bf16x8*)(kr1 + cofs0);
        bf16x8 ak11 = *(const bf16x8*)(kr1 + cofs1);
        bf16x8 ak12 = *(const bf16x8*)(kr1 + cofs2);
        bf16x8 ak13 = *(const bf16x8*)(kr1 + cofs3);

        // ---- S^T = K Q^T for subtiles A and B (K frags reused) ----
        f32x16 scA0 = (f32x16)0.0f, scA1 = (f32x16)0.0f;
        f32x16 scB0 = (f32x16)0.0f, scB1 = (f32x16)0.0f;
        __builtin_amdgcn_s_setprio(1);
        scA0 = __builtin_amdgcn_mfma_f32_32x32x16_bf16(ak00, aqA[0], scA0, 0, 0, 0);
        scA1 = __builtin_amdgcn_mfma_f32_32x32x16_bf16(ak10, aqA[0], scA1, 0, 0, 0);
        scB0 = __builtin_amdgcn_mfma_f32_32x32x16_bf16(ak00, aqB[0], scB0, 0, 0, 0);
        scB1 = __builtin_amdgcn_mfma_f32_32x32x16_bf16(ak10, aqB[0], scB1, 0, 0, 0);
        scA0 = __builtin_amdgcn_mfma_f32_32x32x16_bf16(ak01, aqA[1], scA0, 0, 0, 0);
        scA1 = __builtin_amdgcn_mfma_f32_32x32x16_bf16(ak11, aqA[1], scA1, 0, 0, 0);
        scB0 = __builtin_amdgcn_mfma_f32_32x32x16_bf16(ak01, aqB[1], scB0, 0, 0, 0);
        scB1 = __builtin_amdgcn_mfma_f32_32x32x16_bf16(ak11, aqB[1], scB1, 0, 0, 0);
        scA0 = __builtin_amdgcn_mfma_f32_32x32x16_bf16(ak02, aqA[2], scA0, 0, 0, 0);
        scA1 = __builtin_amdgcn_mfma_f32_32x32x16_bf16(ak12, aqA[2], scA1, 0, 0, 0);
        scB0 = __builtin_amdgcn_mfma_f32_32x32x16_bf16(ak02, aqB[2], scB0, 0, 0, 0);
        scB1 = __builtin_amdgcn_mfma_f32_32x32x16_bf16(ak12, aqB[2], scB1, 0, 0, 0);
        scA0 = __builtin_amdgcn_mfma_f32_32x32x16_bf16(ak03, aqA[3], scA0, 0, 0, 0);
        scA1 = __builtin_amdgcn_mfma_f32_32x32x16_bf16(ak13, aqA[3], scA1, 0, 0, 0);
        scB0 = __builtin_amdgcn_mfma_f32_32x32x16_bf16(ak03, aqB[3], scB0, 0, 0, 0);
        scB1 = __builtin_amdgcn_mfma_f32_32x32x16_bf16(ak13, aqB[3], scB1, 0, 0, 0);
        __builtin_amdgcn_s_setprio(0);

        // ---- V^T frags (shared by both subtiles); latency hides under softmax ----
        bf16x8 av00 = *(const bf16x8*)(vr0 + cofs0);
        bf16x8 av01 = *(const bf16x8*)(vr0 + cofs1);
        bf16x8 av02 = *(const bf16x8*)(vr0 + cofs2);
        bf16x8 av03 = *(const bf16x8*)(vr0 + cofs3);
        bf16x8 av10 = *(const bf16x8*)(vr1 + cofs0);
        bf16x8 av11 = *(const bf16x8*)(vr1 + cofs1);
        bf16x8 av12 = *(const bf16x8*)(vr1 + cofs2);
        bf16x8 av13 = *(const bf16x8*)(vr1 + cofs3);

        // ================= subtile A: softmax + PV =================
        {
            float mx = fmaxf(vmax16(scA0), vmax16(scA1));
            mx = fmaxf(mx, __shfl_xor(mx, 32));
            if (!__all(mx <= mrunA + 8.0f)) {
                float mnew = fmaxf(mrunA, mx);
                float al;  EXP2(al, mrunA - mnew);
                lrunA *= al;
                #pragma unroll
                for (int i = 0; i < 16; ++i) { oA0[i] *= al; oA1[i] *= al; }
                mrunA = mnew;
            }
            #pragma unroll
            for (int i = 0; i < 16; ++i) { float p; EXP2(p, scA0[i] - mrunA); scA0[i] = p; }
            #pragma unroll
            for (int i = 0; i < 16; ++i) { float p; EXP2(p, scA1[i] - mrunA); scA1[i] = p; }
            float r0 = 0.f, r1 = 0.f, r2 = 0.f, r3 = 0.f;
            #pragma unroll
            for (int i = 0; i < 4; ++i) {
                r0 += scA0[i] + scA1[i];     r1 += scA0[4+i] + scA1[4+i];
                r2 += scA0[8+i] + scA1[8+i]; r3 += scA0[12+i] + scA1[12+i];
            }
            float rs = (r0 + r1) + (r2 + r3);
            rs += __shfl_xor(rs, 32);
            lrunA += rs;

            bf16x8 pf0 = make_pf(scA0[0], scA0[1], scA0[2],  scA0[3],  scA0[4],  scA0[5],  scA0[6],  scA0[7]);
            bf16x8 pf1 = make_pf(scA0[8], scA0[9], scA0[10], scA0[11], scA0[12], scA0[13], scA0[14], scA0[15]);
            bf16x8 pf2 = make_pf(scA1[0], scA1[1], scA1[2],  scA1[3],  scA1[4],  scA1[5],  scA1[6],  scA1[7]);
            bf16x8 pf3 = make_pf(scA1[8], scA1[9], scA1[10], scA1[11], scA1[12], scA1[13], scA1[14], scA1[15]);

            __builtin_amdgcn_s_setprio(1);
            oA0 = __builtin_amdgcn_mfma_f32_32x32x16_bf16(av00, pf0, oA0, 0, 0, 0);
            oA1 = __builtin_amdgcn_mfma_f32_32x32x16_bf16(av10, pf0, oA1, 0, 0, 0);
            oA0 = __builtin_amdgcn_mfma_f32_32x32x16_bf16(av01, pf1, oA0, 0, 0, 0);
            oA1 = __builtin_amdgcn_mfma_f32_32x32x16_bf16(av11, pf1, oA1, 0, 0, 0);
            oA0 = __builtin_amdgcn_mfma_f32_32x32x16_bf16(av02, pf2, oA0, 0, 0, 0);
            oA1 = __builtin_amdgcn_mfma_f32_32x32x16_bf16(av12, pf2, oA1, 0, 0, 0);
            oA0 = __builtin_amdgcn_mfma_f32_32x32x16_bf16(av03, pf3, oA0, 0, 0, 0);
            oA1 = __builtin_amdgcn_mfma_f32_32x32x16_bf16(av13, pf3, oA1, 0, 0, 0);
            __builtin_amdgcn_s_setprio(0);
        }

        // ================= subtile B: softmax + PV =================
        {
            float mx = fmaxf(vmax16(scB0), vmax16(scB1));
            mx = fmaxf(mx, __shfl_xor(mx, 32));
            if (!__all(mx <= mrunB + 8.0f)) {
                float mnew = fmaxf(mrunB, mx);
                float al;  EXP2(al, mrunB - mnew);
                lrunB *= al;
                #pragma unroll
                for (int i = 0; i < 16; ++i) { oB0[i] *= al; oB1[i] *= al; }
                mrunB = mnew;
            }
            #pragma unroll
            for (int i = 0; i < 16; ++i) { float p; EXP2(p, scB0[i] - mrunB); scB0[i] = p; }
            #pragma unroll
            for (int i = 0; i < 16; ++i) { float p; EXP2(p, scB1[i] - mrunB); scB1[i] = p; }
            float r0 = 0.f, r1 = 0.f, r2 = 0.f, r3 = 0.f;
            #pragma unroll
            for (int i = 0; i < 4; ++i) {
                r0 += scB0[i] + scB1[i];     r1 += scB0[4+i] + scB1[4+i];
                r2 += scB0[8+i] + scB1[8+i]; r3 += scB0[12+i] + scB1[12+i];
            }
            float rs = (r0 + r1) + (r2 + r3);
            rs += __shfl_xor(rs, 32);
            lrunB += rs;

            bf16x8 pf0 = make_pf(scB0[0], scB0[1], scB0[2],  scB0[3],  scB0[4],  scB0[5],  scB0[6],  scB0[7]);
            bf16x8 pf1 = make_pf(scB0[8], scB0[9], scB0[10], scB0[11], scB0[12], scB0[13], scB0[14], scB0[15]);
            bf16x8 pf2 = make_pf(scB1[0], scB1[1], scB1[2],  scB1[3],  scB1[4],  scB1[5],  scB1[6],  scB1[7]);
            bf16x8 pf3 = make_pf(scB1[8], scB1[9], scB1[10], scB1[11], scB1[12], scB1[13], scB1[14], scB1[15]);

            __builtin_amdgcn_s_setprio(1);
            oB0 = __builtin_amdgcn_mfma_f32_32x32x16_bf16(av00, pf0, oB0, 0, 0, 0);
            oB1 = __builtin_amdgcn_mfma_f32_32x32x16_bf16(av10, pf0, oB1, 0, 0, 0);
            oB0 = __builtin_amdgcn_mfma_f32_32x32x16_bf16(av01, pf1, oB0, 0, 0, 0);
            oB1 = __builtin_amdgcn_mfma_f32_32x32x16_bf16(av11, pf1, oB1, 0, 0, 0);
            oB0 = __builtin_amdgcn_mfma_f32_32x32x16_bf16(av02, pf2, oB0, 0, 0, 0);
            oB1 = __builtin_amdgcn_mfma_f32_32x32x16_bf16(av12, pf2, oB1, 0, 0, 0);
            oB0 = __builtin_amdgcn_mfma_f32_32x32x16_bf16(av03, pf3, oB0, 0, 0, 0);
            oB1 = __builtin_amdgcn_mfma_f32_32x32x16_bf16(av13, pf3, oB1, 0, 0, 0);
            __builtin_amdgcn_s_setprio(0);
        }

        // ---- counted-vmcnt barrier: keep this iter's stage (4 loads) in flight ----
        if (kt + 2 < NT) {
            asm volatile("s_waitcnt vmcnt(4)" ::: "memory");   // retire next tile's loads
            __builtin_amdgcn_s_barrier();
        } else if (kt + 1 < NT) {
            asm volatile("s_waitcnt vmcnt(0)" ::: "memory");   // drain for last tile
            __builtin_amdgcn_s_barrier();
        }
        int tb = b0; b0 = b1; b1 = b2; b2 = tb;
    }
#undef STAGE

    // ---- epilogue: direct f32x4 stores for both subtiles ----
    int b = bh >> 4, h = bh & 15;
    {
        float rl = 1.0f / lrunA;
        float* dst = out + ((size_t)b * SEQ + qbase0 + l31) * D_MODEL + h * DK;
        #pragma unroll
        for (int g = 0; g < 4; ++g) {
            int d0 = 8 * g + 4 * hi;
            f32x4 v0 = { oA0[4*g] * rl, oA0[4*g+1] * rl, oA0[4*g+2] * rl, oA0[4*g+3] * rl };
            *(f32x4*)(dst + d0) = v0;
            f32x4 v1 = { oA1[4*g] * rl, oA1[4*g+1] * rl, oA1[4*g+2] * rl, oA1[4*g+3] * rl };
            *(f32x4*)(dst + 32 + d0) = v1;
        }
    }
    {
        float rl = 1.0f / lrunB;
        float* dst = out + ((size_t)b * SEQ + qbase1 + l31) * D_MODEL + h * DK;
        #pragma unroll
        for (int g = 0; g < 4; ++g) {
            int d0 = 8 * g + 4 * hi;
            f32x4 v0 = { oB0[4*g] * rl, oB0[4*g+1] * rl, oB0[4*g+2] * rl, oB0[4*g+3] * rl };
            *(f32x4*)(dst + d0) = v0;
            f32x4 v1 = { oB1[4*g] * rl, oB1[4*g+1] * rl, oB1[4*g+2] * rl, oB1[4*g+3] * rl };
            *(f32x4*)(dst + 32 + d0) = v1;
        }
    }
}

extern "C" void kernel_launch(void* const* d_in, const int* in_sizes, int n_in,
                              void* d_out, int out_size, void* d_ws, size_t ws_size,
                              hipStream_t stream) {
    const float* x  = (const float*)d_in[0];
    const float* Wq = (const float*)d_in[1];
    const float* bq = (const float*)d_in[2];
    const float* Wk = (const float*)d_in[3];
    const float* bk = (const float*)d_in[4];
    const float* Wv = (const float*)d_in[5];
    const float* bv = (const float*)d_in[6];
    float* out = (float*)d_out;

    unsigned short* xb  = (unsigned short*)d_ws;                       // 16 MB
    unsigned short* wt  = xb + (size_t)MTOT * D_MODEL;                 // 6 MB
    unsigned short* qkv = wt + (size_t)3 * D_MODEL * D_MODEL;          // 48 MB

    cvt_fused_kernel<<<dim3(7168), dim3(256), 0, stream>>>(x, Wq, Wk, Wv, xb, wt);
    qkv_gemm_kernel<<<dim3(24, 64), dim3(256), 0, stream>>>(xb, wt, bq, bk, bv, qkv);
    attn_kernel<<<dim3(64, 8), dim3(256), 0, stream>>>(qkv, out);
}

// Round 16
// 168.931 us; speedup vs baseline: 1.6360x; 1.1178x over previous
//
#include <hip/hip_runtime.h>
#include <stdint.h>

#define D_MODEL 1024
#define NHEAD   16
#define DK      64
#define BATCH   4
#define SEQ     2048
#define MTOT    (BATCH*SEQ)   // 8192
#define KVB     64
#define NT      (SEQ/KVB)     // 32

typedef __attribute__((ext_vector_type(4)))  float  f32x4;
typedef __attribute__((ext_vector_type(16))) float  f32x16;
typedef __attribute__((ext_vector_type(8)))  __bf16 bf16x8;
typedef __attribute__((ext_vector_type(4)))  unsigned short u16x4;
typedef __attribute__((ext_vector_type(8)))  unsigned short u16x8;
typedef __attribute__((ext_vector_type(4)))  unsigned int u32x4;

// Q scale: 1/sqrt(dk) * log2(e)  (softmax computed in exp2 domain)
#define QSCALE 0.1803368801111244f

__device__ __forceinline__ unsigned short f2bf(float f) {
    unsigned u = __builtin_bit_cast(unsigned, f);
    u += 0x7fffu + ((u >> 16) & 1u);
    return (unsigned short)(u >> 16);
}

// ------- fused: x fp32->bf16 convert  +  W[k][n] -> W^T[n][k] bf16 -------
__global__ __launch_bounds__(256) void cvt_fused_kernel(const float* __restrict__ x,
                                                        const float* __restrict__ Wq,
                                                        const float* __restrict__ Wk,
                                                        const float* __restrict__ Wv,
                                                        unsigned short* __restrict__ xb,
                                                        unsigned short* __restrict__ wt) {
    __shared__ float tile[32][33];
    int bid = blockIdx.x;
    int tid = threadIdx.x;
    if (bid < 4096) {
        size_t i = ((size_t)bid * 256 + tid) * 8;
        f32x4 a = *(const f32x4*)(x + i);
        f32x4 b = *(const f32x4*)(x + i + 4);
        u16x8 o;
        o[0] = f2bf(a[0]); o[1] = f2bf(a[1]); o[2] = f2bf(a[2]); o[3] = f2bf(a[3]);
        o[4] = f2bf(b[0]); o[5] = f2bf(b[1]); o[6] = f2bf(b[2]); o[7] = f2bf(b[3]);
        *(u16x8*)(xb + i) = o;
        return;
    }
    int wid = bid - 4096;                 // 0..3071
    int mat = wid >> 10;                  // 0..2
    int r   = wid & 1023;
    int n0  = (r & 31) * 32;
    int k0  = (r >> 5) * 32;
    int tx  = tid & 31;                   // 0..31
    int ty  = tid >> 5;                   // 0..7
    const float* W = (mat == 0) ? Wq : (mat == 1) ? Wk : Wv;
    #pragma unroll
    for (int i = 0; i < 4; ++i)
        tile[ty + i*8][tx] = W[(size_t)(k0 + ty + i*8) * D_MODEL + n0 + tx];
    __syncthreads();
    unsigned short* dst = wt + (size_t)mat * D_MODEL * D_MODEL;
    #pragma unroll
    for (int i = 0; i < 4; ++i)
        dst[(size_t)(n0 + ty + i*8) * D_MODEL + k0 + tx] = f2bf(tile[tx][ty + i*8]);
}

// ---------------- QKV projection GEMM ----------------
// Q,K stored as [b][h][s][dk]; V stored TRANSPOSED as [b][h][dk][s].
#define BM 128
#define BN 128
#define BKK 64
__global__ __launch_bounds__(256) void qkv_gemm_kernel(const unsigned short* __restrict__ xb,
                                                       const unsigned short* __restrict__ wt,
                                                       const float* __restrict__ bq,
                                                       const float* __restrict__ bk,
                                                       const float* __restrict__ bv,
                                                       unsigned short* __restrict__ qkv) {
    __shared__ __align__(16) unsigned char sA[BM * BKK * 2];
    __shared__ __align__(16) unsigned char sB[BN * BKK * 2];

    int lin = blockIdx.y * 24 + blockIdx.x;          // 0..1535
    lin = (lin & 7) * 192 + (lin >> 3);              // bijective XCD-chunk swizzle
    int nb   = lin % 24;
    int mb   = lin / 24;
    int mat  = nb >> 3;
    int col0 = (nb & 7) * BN;
    int m0   = mb * BM;
    int t    = threadIdx.x;
    int lane = t & 63;
    int w    = t >> 6;

    const unsigned short* wmat = wt + (size_t)mat * D_MODEL * D_MODEL;
    const float* bias = (mat == 0) ? bq : (mat == 1) ? bk : bv;

    f32x4 acc[4][4];
    #pragma unroll
    for (int i = 0; i < 4; ++i)
        #pragma unroll
        for (int j = 0; j < 4; ++j)
            acc[i][j] = (f32x4)0.0f;

    int rA = (w >> 1) * 64;
    int rB = (w & 1) * 64;

    for (int ks = 0; ks < D_MODEL / BKK; ++ks) {
        int K0 = ks * BKK;
        #pragma unroll
        for (int i = 0; i < 4; ++i) {
            int c   = t + 256 * i;
            int row = c >> 3;
            int kc  = c & 7;
            int swz = kc ^ (row & 7);
            const unsigned short* ga = xb + (size_t)(m0 + row) * D_MODEL + K0 + swz * 8;
            __builtin_amdgcn_global_load_lds(
                (const __attribute__((address_space(1))) void*)ga,
                (__attribute__((address_space(3))) void*)(sA + c * 16), 16, 0, 0);
            const unsigned short* gb = wmat + (size_t)(col0 + row) * D_MODEL + K0 + swz * 8;
            __builtin_amdgcn_global_load_lds(
                (const __attribute__((address_space(1))) void*)gb,
                (__attribute__((address_space(3))) void*)(sB + c * 16), 16, 0, 0);
        }
        __syncthreads();

        #pragma unroll
        for (int kk = 0; kk < 2; ++kk) {
            bf16x8 af[4], bf[4];
            int kc = kk * 4 + (lane >> 4);
            #pragma unroll
            for (int mt = 0; mt < 4; ++mt) {
                int row = rA + mt * 16 + (lane & 15);
                int swz = kc ^ (row & 7);
                af[mt] = *(const bf16x8*)(sA + row * 128 + swz * 16);
            }
            #pragma unroll
            for (int nt = 0; nt < 4; ++nt) {
                int row = rB + nt * 16 + (lane & 15);
                int swz = kc ^ (row & 7);
                bf[nt] = *(const bf16x8*)(sB + row * 128 + swz * 16);
            }
            #pragma unroll
            for (int mt = 0; mt < 4; ++mt)
                #pragma unroll
                for (int nt = 0; nt < 4; ++nt)
                    acc[mt][nt] = __builtin_amdgcn_mfma_f32_16x16x32_bf16(
                        af[mt], bf[nt], acc[mt][nt], 0, 0, 0);
        }
        __syncthreads();
    }

    if (mat == 2) {
        // V: pack the 4 r-values (4 consecutive s at fixed d) into one 8B store.
        // V^T layout [b][h][d][s] makes them contiguous. 16 stores/lane vs 64.
        #pragma unroll
        for (int mt = 0; mt < 4; ++mt) {
            int gm0 = m0 + rA + mt * 16 + (lane >> 4) * 4;
            int b = gm0 >> 11, s0 = gm0 & 2047;
            #pragma unroll
            for (int nt = 0; nt < 4; ++nt) {
                int gn = col0 + rB + nt * 16 + (lane & 15);
                float bval = bias[gn];
                int h = gn >> 6, d = gn & 63;
                u16x4 pk;
                #pragma unroll
                for (int r = 0; r < 4; ++r)
                    pk[r] = f2bf(acc[mt][nt][r] + bval);
                *(u16x4*)(qkv + (size_t)2 * MTOT * D_MODEL +
                          ((size_t)(b * NHEAD + h) * DK + d) * SEQ + s0) = pk;
            }
        }
    } else {
        #pragma unroll
        for (int mt = 0; mt < 4; ++mt) {
            #pragma unroll
            for (int nt = 0; nt < 4; ++nt) {
                int gn = col0 + rB + nt * 16 + (lane & 15);
                float bval = bias[gn];
                #pragma unroll
                for (int r = 0; r < 4; ++r) {
                    int gm = m0 + rA + mt * 16 + (lane >> 4) * 4 + r;
                    float v = acc[mt][nt][r] + bval;
                    if (mat == 0) v *= QSCALE;   // fold 1/sqrt(dk)*log2e into Q
                    int b = gm >> 11, s = gm & 2047;
                    int h = gn >> 6,  d = gn & 63;
                    qkv[(size_t)mat * MTOT * D_MODEL +
                        ((size_t)(b * NHEAD + h) * SEQ + s) * DK + d] = f2bf(v);
                }
            }
        }
    }
}

// ---------------- fused flash attention (swapped-QK^T, 32x32 MFMA, LDS-staged) ----------------
// grid: (64 bh, 8 q-blocks of 256), 256 threads = 4 waves, each wave 64 q-rows
// (two 32-row subtiles A/B sharing every K/V LDS fragment). Triple-buffered
// K/V in LDS, counted vmcnt; r15-verified.
// LDS: K bufs [0,24576) = 3 x 8K | V^T bufs [24576,49152) = 3 x 8K
#define CVTPK(dst, lo_, hi_) \
    asm("v_cvt_pk_bf16_f32 %0, %1, %2" : "=v"(dst) : "v"(lo_), "v"(hi_))
#define PLSWAP(x_, y_) \
    asm("v_permlane32_swap_b32 %0, %1" : "+v"(x_), "+v"(y_))
#define EXP2(dst, x_) \
    asm("v_exp_f32 %0, %1" : "=v"(dst) : "v"(x_))

// P^T B-frag from 8 per-lane P values (C-layout kv rows) via cvt_pk+permlane32_swap.
__device__ __forceinline__ bf16x8 make_pf(float p0, float p1, float p2, float p3,
                                          float p4, float p5, float p6, float p7) {
    unsigned a1, a2, b1, b2;
    CVTPK(a1, p0, p1); CVTPK(a2, p2, p3);
    CVTPK(b1, p4, p5); CVTPK(b2, p6, p7);
    PLSWAP(a1, b1); PLSWAP(a2, b2);
    u32x4 u = { a1, a2, b1, b2 };
    return __builtin_bit_cast(bf16x8, u);
}

// max of 16 via v_max3-fusable nests (T17)
__device__ __forceinline__ float vmax16(const f32x16& v) {
    float a = fmaxf(fmaxf(v[0],  v[1]),  v[2]);
    float b = fmaxf(fmaxf(v[3],  v[4]),  v[5]);
    float c = fmaxf(fmaxf(v[6],  v[7]),  v[8]);
    float d = fmaxf(fmaxf(v[9],  v[10]), v[11]);
    a = fmaxf(fmaxf(a, v[12]), v[13]);
    b = fmaxf(fmaxf(b, v[14]), v[15]);
    return fmaxf(fmaxf(a, b), fmaxf(c, d));
}

__global__ __launch_bounds__(256, 2) void attn_kernel(const unsigned short* __restrict__ qkv,
                                                      float* __restrict__ out) {
    __shared__ __align__(16) unsigned char lds[49152];

    int bh = blockIdx.x;      // b*16 + h
    int qb = blockIdx.y;      // 0..7
    int t = threadIdx.x;      // 0..255
    int lane = t & 63;
    int w = t >> 6;           // 0..3
    int hi = lane >> 5;       // 0/1
    int l31 = lane & 31;

    const unsigned short* Qb = qkv + (size_t)bh * SEQ * DK;
    const unsigned short* Kb = qkv + (size_t)MTOT * D_MODEL + (size_t)bh * SEQ * DK;
    const unsigned short* Vt = qkv + (size_t)2 * MTOT * D_MODEL + (size_t)bh * DK * SEQ; // [d][s]

    int qbase0 = qb * 256 + w * 64;       // subtile A
    int qbase1 = qbase0 + 32;             // subtile B

    // Q B-frags for both subtiles: col=q=lane&31, k=d=kd*16+hi*8+j
    bf16x8 aqA[4], aqB[4];
    #pragma unroll
    for (int kd = 0; kd < 4; ++kd) {
        aqA[kd] = *(const bf16x8*)(Qb + (size_t)(qbase0 + l31) * DK + kd * 16 + hi * 8);
        aqB[kd] = *(const bf16x8*)(Qb + (size_t)(qbase1 + l31) * DK + kd * 16 + hi * 8);
    }

    f32x16 oA0 = (f32x16)0.0f, oA1 = (f32x16)0.0f;
    f32x16 oB0 = (f32x16)0.0f, oB1 = (f32x16)0.0f;
    float mrunA = -3e38f, lrunA = 0.0f;
    float mrunB = -3e38f, lrunB = 0.0f;

    // Stage tile into buffer slot b_: 256 threads x 2 chunks (K and V each 8KB).
#define STAGE(tile_, b_) do {                                                          \
    int kv0_ = (tile_) * KVB;                                                          \
    _Pragma("unroll")                                                                  \
    for (int i_ = 0; i_ < 2; ++i_) {                                                   \
        int c_ = t + 256 * i_;                                                         \
        int row_ = c_ >> 3, kc_ = c_ & 7;                                              \
        int sw_ = (kc_ ^ (row_ & 7)) * 8;                                              \
        __builtin_amdgcn_global_load_lds(                                              \
            (const __attribute__((address_space(1))) void*)(Kb + (size_t)(kv0_ + row_) * DK + sw_), \
            (__attribute__((address_space(3))) void*)(lds + (b_) * 8192 + c_ * 16), 16, 0, 0);      \
        __builtin_amdgcn_global_load_lds(                                              \
            (const __attribute__((address_space(1))) void*)(Vt + (size_t)row_ * SEQ + kv0_ + sw_),  \
            (__attribute__((address_space(3))) void*)(lds + 24576 + (b_) * 8192 + c_ * 16), 16, 0, 0); \
    }                                                                                  \
} while (0)

    int swz7 = l31 & 7;
    int cofs0 = ((0 + hi) ^ swz7) << 4;
    int cofs1 = ((2 + hi) ^ swz7) << 4;
    int cofs2 = ((4 + hi) ^ swz7) << 4;
    int cofs3 = ((6 + hi) ^ swz7) << 4;

    // Prologue: stage tiles 0 and 1; wait only tile 0 (4 loads/thread in flight -> 2 remain).
    STAGE(0, 0);
    STAGE(1, 1);
    asm volatile("s_waitcnt vmcnt(4)" ::: "memory");
    __builtin_amdgcn_s_barrier();

    int b0 = 0, b1 = 1, b2 = 2;

    for (int kt = 0; kt < NT; ++kt) {
        if (kt + 2 < NT)
            STAGE(kt + 2, b2);

        const unsigned char* kb = lds + b0 * 8192;
        const unsigned char* vb = lds + 24576 + b0 * 8192;
        const unsigned char* kr0 = kb + l31 * 128;
        const unsigned char* kr1 = kb + (32 + l31) * 128;
        const unsigned char* vr0 = vb + l31 * 128;
        const unsigned char* vr1 = vb + (32 + l31) * 128;

        // ---- K frags (shared by both subtiles) ----
        bf16x8 ak00 = *(const bf16x8*)(kr0 + cofs0);
        bf16x8 ak01 = *(const bf16x8*)(kr0 + cofs1);
        bf16x8 ak02 = *(const bf16x8*)(kr0 + cofs2);
        bf16x8 ak03 = *(const bf16x8*)(kr0 + cofs3);
        bf16x8 ak10 = *(const bf16x8*)(kr1 + cofs0);
        bf16x8 ak11 = *(const bf16x8*)(kr1 + cofs1);
        bf16x8 ak12 = *(const bf16x8*)(kr1 + cofs2);
        bf16x8 ak13 = *(const bf16x8*)(kr1 + cofs3);

        // ---- S^T = K Q^T for subtiles A and B (K frags reused) ----
        f32x16 scA0 = (f32x16)0.0f, scA1 = (f32x16)0.0f;
        f32x16 scB0 = (f32x16)0.0f, scB1 = (f32x16)0.0f;
        __builtin_amdgcn_s_setprio(1);
        scA0 = __builtin_amdgcn_mfma_f32_32x32x16_bf16(ak00, aqA[0], scA0, 0, 0, 0);
        scA1 = __builtin_amdgcn_mfma_f32_32x32x16_bf16(ak10, aqA[0], scA1, 0, 0, 0);
        scB0 = __builtin_amdgcn_mfma_f32_32x32x16_bf16(ak00, aqB[0], scB0, 0, 0, 0);
        scB1 = __builtin_amdgcn_mfma_f32_32x32x16_bf16(ak10, aqB[0], scB1, 0, 0, 0);
        scA0 = __builtin_amdgcn_mfma_f32_32x32x16_bf16(ak01, aqA[1], scA0, 0, 0, 0);
        scA1 = __builtin_amdgcn_mfma_f32_32x32x16_bf16(ak11, aqA[1], scA1, 0, 0, 0);
        scB0 = __builtin_amdgcn_mfma_f32_32x32x16_bf16(ak01, aqB[1], scB0, 0, 0, 0);
        scB1 = __builtin_amdgcn_mfma_f32_32x32x16_bf16(ak11, aqB[1], scB1, 0, 0, 0);
        scA0 = __builtin_amdgcn_mfma_f32_32x32x16_bf16(ak02, aqA[2], scA0, 0, 0, 0);
        scA1 = __builtin_amdgcn_mfma_f32_32x32x16_bf16(ak12, aqA[2], scA1, 0, 0, 0);
        scB0 = __builtin_amdgcn_mfma_f32_32x32x16_bf16(ak02, aqB[2], scB0, 0, 0, 0);
        scB1 = __builtin_amdgcn_mfma_f32_32x32x16_bf16(ak12, aqB[2], scB1, 0, 0, 0);
        scA0 = __builtin_amdgcn_mfma_f32_32x32x16_bf16(ak03, aqA[3], scA0, 0, 0, 0);
        scA1 = __builtin_amdgcn_mfma_f32_32x32x16_bf16(ak13, aqA[3], scA1, 0, 0, 0);
        scB0 = __builtin_amdgcn_mfma_f32_32x32x16_bf16(ak03, aqB[3], scB0, 0, 0, 0);
        scB1 = __builtin_amdgcn_mfma_f32_32x32x16_bf16(ak13, aqB[3], scB1, 0, 0, 0);
        __builtin_amdgcn_s_setprio(0);

        // ---- V^T frags (shared by both subtiles); latency hides under softmax ----
        bf16x8 av00 = *(const bf16x8*)(vr0 + cofs0);
        bf16x8 av01 = *(const bf16x8*)(vr0 + cofs1);
        bf16x8 av02 = *(const bf16x8*)(vr0 + cofs2);
        bf16x8 av03 = *(const bf16x8*)(vr0 + cofs3);
        bf16x8 av10 = *(const bf16x8*)(vr1 + cofs0);
        bf16x8 av11 = *(const bf16x8*)(vr1 + cofs1);
        bf16x8 av12 = *(const bf16x8*)(vr1 + cofs2);
        bf16x8 av13 = *(const bf16x8*)(vr1 + cofs3);

        // ================= subtile A: softmax + PV =================
        {
            float mx = fmaxf(vmax16(scA0), vmax16(scA1));
            mx = fmaxf(mx, __shfl_xor(mx, 32));
            if (!__all(mx <= mrunA + 8.0f)) {
                float mnew = fmaxf(mrunA, mx);
                float al;  EXP2(al, mrunA - mnew);
                lrunA *= al;
                #pragma unroll
                for (int i = 0; i < 16; ++i) { oA0[i] *= al; oA1[i] *= al; }
                mrunA = mnew;
            }
            #pragma unroll
            for (int i = 0; i < 16; ++i) { float p; EXP2(p, scA0[i] - mrunA); scA0[i] = p; }
            #pragma unroll
            for (int i = 0; i < 16; ++i) { float p; EXP2(p, scA1[i] - mrunA); scA1[i] = p; }
            float r0 = 0.f, r1 = 0.f, r2 = 0.f, r3 = 0.f;
            #pragma unroll
            for (int i = 0; i < 4; ++i) {
                r0 += scA0[i] + scA1[i];     r1 += scA0[4+i] + scA1[4+i];
                r2 += scA0[8+i] + scA1[8+i]; r3 += scA0[12+i] + scA1[12+i];
            }
            float rs = (r0 + r1) + (r2 + r3);
            rs += __shfl_xor(rs, 32);
            lrunA += rs;

            bf16x8 pf0 = make_pf(scA0[0], scA0[1], scA0[2],  scA0[3],  scA0[4],  scA0[5],  scA0[6],  scA0[7]);
            bf16x8 pf1 = make_pf(scA0[8], scA0[9], scA0[10], scA0[11], scA0[12], scA0[13], scA0[14], scA0[15]);
            bf16x8 pf2 = make_pf(scA1[0], scA1[1], scA1[2],  scA1[3],  scA1[4],  scA1[5],  scA1[6],  scA1[7]);
            bf16x8 pf3 = make_pf(scA1[8], scA1[9], scA1[10], scA1[11], scA1[12], scA1[13], scA1[14], scA1[15]);

            __builtin_amdgcn_s_setprio(1);
            oA0 = __builtin_amdgcn_mfma_f32_32x32x16_bf16(av00, pf0, oA0, 0, 0, 0);
            oA1 = __builtin_amdgcn_mfma_f32_32x32x16_bf16(av10, pf0, oA1, 0, 0, 0);
            oA0 = __builtin_amdgcn_mfma_f32_32x32x16_bf16(av01, pf1, oA0, 0, 0, 0);
            oA1 = __builtin_amdgcn_mfma_f32_32x32x16_bf16(av11, pf1, oA1, 0, 0, 0);
            oA0 = __builtin_amdgcn_mfma_f32_32x32x16_bf16(av02, pf2, oA0, 0, 0, 0);
            oA1 = __builtin_amdgcn_mfma_f32_32x32x16_bf16(av12, pf2, oA1, 0, 0, 0);
            oA0 = __builtin_amdgcn_mfma_f32_32x32x16_bf16(av03, pf3, oA0, 0, 0, 0);
            oA1 = __builtin_amdgcn_mfma_f32_32x32x16_bf16(av13, pf3, oA1, 0, 0, 0);
            __builtin_amdgcn_s_setprio(0);
        }

        // ================= subtile B: softmax + PV =================
        {
            float mx = fmaxf(vmax16(scB0), vmax16(scB1));
            mx = fmaxf(mx, __shfl_xor(mx, 32));
            if (!__all(mx <= mrunB + 8.0f)) {
                float mnew = fmaxf(mrunB, mx);
                float al;  EXP2(al, mrunB - mnew);
                lrunB *= al;
                #pragma unroll
                for (int i = 0; i < 16; ++i) { oB0[i] *= al; oB1[i] *= al; }
                mrunB = mnew;
            }
            #pragma unroll
            for (int i = 0; i < 16; ++i) { float p; EXP2(p, scB0[i] - mrunB); scB0[i] = p; }
            #pragma unroll
            for (int i = 0; i < 16; ++i) { float p; EXP2(p, scB1[i] - mrunB); scB1[i] = p; }
            float r0 = 0.f, r1 = 0.f, r2 = 0.f, r3 = 0.f;
            #pragma unroll
            for (int i = 0; i < 4; ++i) {
                r0 += scB0[i] + scB1[i];     r1 += scB0[4+i] + scB1[4+i];
                r2 += scB0[8+i] + scB1[8+i]; r3 += scB0[12+i] + scB1[12+i];
            }
            float rs = (r0 + r1) + (r2 + r3);
            rs += __shfl_xor(rs, 32);
            lrunB += rs;

            bf16x8 pf0 = make_pf(scB0[0], scB0[1], scB0[2],  scB0[3],  scB0[4],  scB0[5],  scB0[6],  scB0[7]);
            bf16x8 pf1 = make_pf(scB0[8], scB0[9], scB0[10], scB0[11], scB0[12], scB0[13], scB0[14], scB0[15]);
            bf16x8 pf2 = make_pf(scB1[0], scB1[1], scB1[2],  scB1[3],  scB1[4],  scB1[5],  scB1[6],  scB1[7]);
            bf16x8 pf3 = make_pf(scB1[8], scB1[9], scB1[10], scB1[11], scB1[12], scB1[13], scB1[14], scB1[15]);

            __builtin_amdgcn_s_setprio(1);
            oB0 = __builtin_amdgcn_mfma_f32_32x32x16_bf16(av00, pf0, oB0, 0, 0, 0);
            oB1 = __builtin_amdgcn_mfma_f32_32x32x16_bf16(av10, pf0, oB1, 0, 0, 0);
            oB0 = __builtin_amdgcn_mfma_f32_32x32x16_bf16(av01, pf1, oB0, 0, 0, 0);
            oB1 = __builtin_amdgcn_mfma_f32_32x32x16_bf16(av11, pf1, oB1, 0, 0, 0);
            oB0 = __builtin_amdgcn_mfma_f32_32x32x16_bf16(av02, pf2, oB0, 0, 0, 0);
            oB1 = __builtin_amdgcn_mfma_f32_32x32x16_bf16(av12, pf2, oB1, 0, 0, 0);
            oB0 = __builtin_amdgcn_mfma_f32_32x32x16_bf16(av03, pf3, oB0, 0, 0, 0);
            oB1 = __builtin_amdgcn_mfma_f32_32x32x16_bf16(av13, pf3, oB1, 0, 0, 0);
            __builtin_amdgcn_s_setprio(0);
        }

        // ---- counted-vmcnt barrier: keep this iter's stage (4 loads) in flight ----
        if (kt + 2 < NT) {
            asm volatile("s_waitcnt vmcnt(4)" ::: "memory");   // retire next tile's loads
            __builtin_amdgcn_s_barrier();
        } else if (kt + 1 < NT) {
            asm volatile("s_waitcnt vmcnt(0)" ::: "memory");   // drain for last tile
            __builtin_amdgcn_s_barrier();
        }
        int tb = b0; b0 = b1; b1 = b2; b2 = tb;
    }
#undef STAGE

    // ---- epilogue: direct f32x4 stores for both subtiles ----
    int b = bh >> 4, h = bh & 15;
    {
        float rl = 1.0f / lrunA;
        float* dst = out + ((size_t)b * SEQ + qbase0 + l31) * D_MODEL + h * DK;
        #pragma unroll
        for (int g = 0; g < 4; ++g) {
            int d0 = 8 * g + 4 * hi;
            f32x4 v0 = { oA0[4*g] * rl, oA0[4*g+1] * rl, oA0[4*g+2] * rl, oA0[4*g+3] * rl };
            *(f32x4*)(dst + d0) = v0;
            f32x4 v1 = { oA1[4*g] * rl, oA1[4*g+1] * rl, oA1[4*g+2] * rl, oA1[4*g+3] * rl };
            *(f32x4*)(dst + 32 + d0) = v1;
        }
    }
    {
        float rl = 1.0f / lrunB;
        float* dst = out + ((size_t)b * SEQ + qbase1 + l31) * D_MODEL + h * DK;
        #pragma unroll
        for (int g = 0; g < 4; ++g) {
            int d0 = 8 * g + 4 * hi;
            f32x4 v0 = { oB0[4*g] * rl, oB0[4*g+1] * rl, oB0[4*g+2] * rl, oB0[4*g+3] * rl };
            *(f32x4*)(dst + d0) = v0;
            f32x4 v1 = { oB1[4*g] * rl, oB1[4*g+1] * rl, oB1[4*g+2] * rl, oB1[4*g+3] * rl };
            *(f32x4*)(dst + 32 + d0) = v1;
        }
    }
}

extern "C" void kernel_launch(void* const* d_in, const int* in_sizes, int n_in,
                              void* d_out, int out_size, void* d_ws, size_t ws_size,
                              hipStream_t stream) {
    const float* x  = (const float*)d_in[0];
    const float* Wq = (const float*)d_in[1];
    const float* bq = (const float*)d_in[2];
    const float* Wk = (const float*)d_in[3];
    const float* bk = (const float*)d_in[4];
    const float* Wv = (const float*)d_in[5];
    const float* bv = (const float*)d_in[6];
    float* out = (float*)d_out;

    unsigned short* xb  = (unsigned short*)d_ws;                       // 16 MB
    unsigned short* wt  = xb + (size_t)MTOT * D_MODEL;                 // 6 MB
    unsigned short* qkv = wt + (size_t)3 * D_MODEL * D_MODEL;          // 48 MB

    cvt_fused_kernel<<<dim3(7168), dim3(256), 0, stream>>>(x, Wq, Wk, Wv, xb, wt);
    qkv_gemm_kernel<<<dim3(24, 64), dim3(256), 0, stream>>>(xb, wt, bq, bk, bv, qkv);
    attn_kernel<<<dim3(64, 8), dim3(256), 0, stream>>>(qkv, out);
}

// Round 17
// 160.618 us; speedup vs baseline: 1.7207x; 1.0518x over previous
//
#include <hip/hip_runtime.h>
#include <stdint.h>

#define D_MODEL 1024
#define NHEAD   16
#define DK      64
#define BATCH   4
#define SEQ     2048
#define MTOT    (BATCH*SEQ)   // 8192
#define KVB     64
#define NT      (SEQ/KVB)     // 32

typedef __attribute__((ext_vector_type(4)))  float  f32x4;
typedef __attribute__((ext_vector_type(16))) float  f32x16;
typedef __attribute__((ext_vector_type(8)))  __bf16 bf16x8;
typedef __attribute__((ext_vector_type(4)))  unsigned short u16x4;
typedef __attribute__((ext_vector_type(8)))  unsigned short u16x8;
typedef __attribute__((ext_vector_type(4)))  unsigned int u32x4;

// Q scale: 1/sqrt(dk) * log2(e)  (softmax computed in exp2 domain)
#define QSCALE 0.1803368801111244f

__device__ __forceinline__ unsigned short f2bf(float f) {
    unsigned u = __builtin_bit_cast(unsigned, f);
    u += 0x7fffu + ((u >> 16) & 1u);
    return (unsigned short)(u >> 16);
}

// ------- fused: x fp32->bf16 convert  +  W[k][n] -> W^T[n][k] bf16 -------
__global__ __launch_bounds__(256) void cvt_fused_kernel(const float* __restrict__ x,
                                                        const float* __restrict__ Wq,
                                                        const float* __restrict__ Wk,
                                                        const float* __restrict__ Wv,
                                                        unsigned short* __restrict__ xb,
                                                        unsigned short* __restrict__ wt) {
    __shared__ float tile[32][33];
    int bid = blockIdx.x;
    int tid = threadIdx.x;
    if (bid < 4096) {
        size_t i = ((size_t)bid * 256 + tid) * 8;
        f32x4 a = *(const f32x4*)(x + i);
        f32x4 b = *(const f32x4*)(x + i + 4);
        u16x8 o;
        o[0] = f2bf(a[0]); o[1] = f2bf(a[1]); o[2] = f2bf(a[2]); o[3] = f2bf(a[3]);
        o[4] = f2bf(b[0]); o[5] = f2bf(b[1]); o[6] = f2bf(b[2]); o[7] = f2bf(b[3]);
        *(u16x8*)(xb + i) = o;
        return;
    }
    int wid = bid - 4096;                 // 0..3071
    int mat = wid >> 10;                  // 0..2
    int r   = wid & 1023;
    int n0  = (r & 31) * 32;
    int k0  = (r >> 5) * 32;
    int tx  = tid & 31;                   // 0..31
    int ty  = tid >> 5;                   // 0..7
    const float* W = (mat == 0) ? Wq : (mat == 1) ? Wk : Wv;
    #pragma unroll
    for (int i = 0; i < 4; ++i)
        tile[ty + i*8][tx] = W[(size_t)(k0 + ty + i*8) * D_MODEL + n0 + tx];
    __syncthreads();
    unsigned short* dst = wt + (size_t)mat * D_MODEL * D_MODEL;
    #pragma unroll
    for (int i = 0; i < 4; ++i)
        dst[(size_t)(n0 + ty + i*8) * D_MODEL + k0 + tx] = f2bf(tile[tx][ty + i*8]);
}

// ---------------- QKV projection GEMM (paired m-tiles sharing B) ----------------
// Each block: two 128x128 m-tiles (m0, m0+128) x one n-tile; B staged once.
// Q,K stored as [b][h][s][dk]; V stored TRANSPOSED as [b][h][dk][s].
#define BM 128
#define BN 128
#define BKK 64
__global__ __launch_bounds__(256, 2) void qkv_gemm_kernel(const unsigned short* __restrict__ xb,
                                                          const unsigned short* __restrict__ wt,
                                                          const float* __restrict__ bq,
                                                          const float* __restrict__ bk,
                                                          const float* __restrict__ bv,
                                                          unsigned short* __restrict__ qkv) {
    __shared__ __align__(16) unsigned char sA0[BM * BKK * 2];   // 16KB
    __shared__ __align__(16) unsigned char sA1[BM * BKK * 2];   // 16KB
    __shared__ __align__(16) unsigned char sB [BN * BKK * 2];   // 16KB

    int lin = blockIdx.y * 24 + blockIdx.x;          // 0..767
    lin = (lin & 7) * 96 + (lin >> 3);               // bijective XCD-chunk swizzle (768 = 8*96)
    int nb   = lin % 24;
    int mb   = lin / 24;                             // 0..31
    int mat  = nb >> 3;
    int col0 = (nb & 7) * BN;
    int m0   = mb * 256;                             // pair of m-tiles: m0, m0+128
    int t    = threadIdx.x;
    int lane = t & 63;
    int w    = t >> 6;

    const unsigned short* wmat = wt + (size_t)mat * D_MODEL * D_MODEL;
    const float* bias = (mat == 0) ? bq : (mat == 1) ? bk : bv;

    f32x4 acc0[4][4], acc1[4][4];
    #pragma unroll
    for (int i = 0; i < 4; ++i)
        #pragma unroll
        for (int j = 0; j < 4; ++j) {
            acc0[i][j] = (f32x4)0.0f;
            acc1[i][j] = (f32x4)0.0f;
        }

    int rA = (w >> 1) * 64;
    int rB = (w & 1) * 64;

    for (int ks = 0; ks < D_MODEL / BKK; ++ks) {
        int K0 = ks * BKK;
        #pragma unroll
        for (int i = 0; i < 4; ++i) {
            int c   = t + 256 * i;
            int row = c >> 3;
            int kc  = c & 7;
            int swz = kc ^ (row & 7);
            const unsigned short* ga0 = xb + (size_t)(m0 + row) * D_MODEL + K0 + swz * 8;
            __builtin_amdgcn_global_load_lds(
                (const __attribute__((address_space(1))) void*)ga0,
                (__attribute__((address_space(3))) void*)(sA0 + c * 16), 16, 0, 0);
            const unsigned short* ga1 = xb + (size_t)(m0 + 128 + row) * D_MODEL + K0 + swz * 8;
            __builtin_amdgcn_global_load_lds(
                (const __attribute__((address_space(1))) void*)ga1,
                (__attribute__((address_space(3))) void*)(sA1 + c * 16), 16, 0, 0);
            const unsigned short* gb = wmat + (size_t)(col0 + row) * D_MODEL + K0 + swz * 8;
            __builtin_amdgcn_global_load_lds(
                (const __attribute__((address_space(1))) void*)gb,
                (__attribute__((address_space(3))) void*)(sB + c * 16), 16, 0, 0);
        }
        __syncthreads();

        #pragma unroll
        for (int kk = 0; kk < 2; ++kk) {
            bf16x8 af0[4], af1[4], bf[4];
            int kc = kk * 4 + (lane >> 4);
            #pragma unroll
            for (int mt = 0; mt < 4; ++mt) {
                int row = rA + mt * 16 + (lane & 15);
                int swz = kc ^ (row & 7);
                af0[mt] = *(const bf16x8*)(sA0 + row * 128 + swz * 16);
                af1[mt] = *(const bf16x8*)(sA1 + row * 128 + swz * 16);
            }
            #pragma unroll
            for (int nt = 0; nt < 4; ++nt) {
                int row = rB + nt * 16 + (lane & 15);
                int swz = kc ^ (row & 7);
                bf[nt] = *(const bf16x8*)(sB + row * 128 + swz * 16);
            }
            #pragma unroll
            for (int mt = 0; mt < 4; ++mt)
                #pragma unroll
                for (int nt = 0; nt < 4; ++nt) {
                    acc0[mt][nt] = __builtin_amdgcn_mfma_f32_16x16x32_bf16(
                        af0[mt], bf[nt], acc0[mt][nt], 0, 0, 0);
                    acc1[mt][nt] = __builtin_amdgcn_mfma_f32_16x16x32_bf16(
                        af1[mt], bf[nt], acc1[mt][nt], 0, 0, 0);
                }
        }
        __syncthreads();
    }

    // ---- epilogue (run for each m-subtile) ----
    #pragma unroll
    for (int half = 0; half < 2; ++half) {
        int mbase = m0 + half * 128;
        if (mat == 2) {
            // V: pack 4 r-values (consecutive s at fixed d) into one 8B store.
            #pragma unroll
            for (int mt = 0; mt < 4; ++mt) {
                int gm0 = mbase + rA + mt * 16 + (lane >> 4) * 4;
                int b = gm0 >> 11, s0 = gm0 & 2047;
                #pragma unroll
                for (int nt = 0; nt < 4; ++nt) {
                    int gn = col0 + rB + nt * 16 + (lane & 15);
                    float bval = bias[gn];
                    int h = gn >> 6, d = gn & 63;
                    u16x4 pk;
                    #pragma unroll
                    for (int r = 0; r < 4; ++r) {
                        float v = half ? acc1[mt][nt][r] : acc0[mt][nt][r];
                        pk[r] = f2bf(v + bval);
                    }
                    *(u16x4*)(qkv + (size_t)2 * MTOT * D_MODEL +
                              ((size_t)(b * NHEAD + h) * DK + d) * SEQ + s0) = pk;
                }
            }
        } else {
            #pragma unroll
            for (int mt = 0; mt < 4; ++mt) {
                #pragma unroll
                for (int nt = 0; nt < 4; ++nt) {
                    int gn = col0 + rB + nt * 16 + (lane & 15);
                    float bval = bias[gn];
                    #pragma unroll
                    for (int r = 0; r < 4; ++r) {
                        int gm = mbase + rA + mt * 16 + (lane >> 4) * 4 + r;
                        float v = (half ? acc1[mt][nt][r] : acc0[mt][nt][r]) + bval;
                        if (mat == 0) v *= QSCALE;   // fold 1/sqrt(dk)*log2e into Q
                        int b = gm >> 11, s = gm & 2047;
                        int h = gn >> 6,  d = gn & 63;
                        qkv[(size_t)mat * MTOT * D_MODEL +
                            ((size_t)(b * NHEAD + h) * SEQ + s) * DK + d] = f2bf(v);
                    }
                }
            }
        }
    }
}

// ---------------- fused flash attention (swapped-QK^T, 32x32 MFMA, LDS-staged) ----------------
// grid: (64 bh, 8 q-blocks of 256), 256 threads = 4 waves, each wave 64 q-rows
// (two 32-row subtiles A/B sharing every K/V LDS fragment). Triple-buffered
// K/V in LDS, counted vmcnt; r16-verified (byte-identical).
// LDS: K bufs [0,24576) = 3 x 8K | V^T bufs [24576,49152) = 3 x 8K
#define CVTPK(dst, lo_, hi_) \
    asm("v_cvt_pk_bf16_f32 %0, %1, %2" : "=v"(dst) : "v"(lo_), "v"(hi_))
#define PLSWAP(x_, y_) \
    asm("v_permlane32_swap_b32 %0, %1" : "+v"(x_), "+v"(y_))
#define EXP2(dst, x_) \
    asm("v_exp_f32 %0, %1" : "=v"(dst) : "v"(x_))

// P^T B-frag from 8 per-lane P values (C-layout kv rows) via cvt_pk+permlane32_swap.
__device__ __forceinline__ bf16x8 make_pf(float p0, float p1, float p2, float p3,
                                          float p4, float p5, float p6, float p7) {
    unsigned a1, a2, b1, b2;
    CVTPK(a1, p0, p1); CVTPK(a2, p2, p3);
    CVTPK(b1, p4, p5); CVTPK(b2, p6, p7);
    PLSWAP(a1, b1); PLSWAP(a2, b2);
    u32x4 u = { a1, a2, b1, b2 };
    return __builtin_bit_cast(bf16x8, u);
}

// max of 16 via v_max3-fusable nests (T17)
__device__ __forceinline__ float vmax16(const f32x16& v) {
    float a = fmaxf(fmaxf(v[0],  v[1]),  v[2]);
    float b = fmaxf(fmaxf(v[3],  v[4]),  v[5]);
    float c = fmaxf(fmaxf(v[6],  v[7]),  v[8]);
    float d = fmaxf(fmaxf(v[9],  v[10]), v[11]);
    a = fmaxf(fmaxf(a, v[12]), v[13]);
    b = fmaxf(fmaxf(b, v[14]), v[15]);
    return fmaxf(fmaxf(a, b), fmaxf(c, d));
}

__global__ __launch_bounds__(256, 2) void attn_kernel(const unsigned short* __restrict__ qkv,
                                                      float* __restrict__ out) {
    __shared__ __align__(16) unsigned char lds[49152];

    int bh = blockIdx.x;      // b*16 + h
    int qb = blockIdx.y;      // 0..7
    int t = threadIdx.x;      // 0..255
    int lane = t & 63;
    int w = t >> 6;           // 0..3
    int hi = lane >> 5;       // 0/1
    int l31 = lane & 31;

    const unsigned short* Qb = qkv + (size_t)bh * SEQ * DK;
    const unsigned short* Kb = qkv + (size_t)MTOT * D_MODEL + (size_t)bh * SEQ * DK;
    const unsigned short* Vt = qkv + (size_t)2 * MTOT * D_MODEL + (size_t)bh * DK * SEQ; // [d][s]

    int qbase0 = qb * 256 + w * 64;       // subtile A
    int qbase1 = qbase0 + 32;             // subtile B

    // Q B-frags for both subtiles: col=q=lane&31, k=d=kd*16+hi*8+j
    bf16x8 aqA[4], aqB[4];
    #pragma unroll
    for (int kd = 0; kd < 4; ++kd) {
        aqA[kd] = *(const bf16x8*)(Qb + (size_t)(qbase0 + l31) * DK + kd * 16 + hi * 8);
        aqB[kd] = *(const bf16x8*)(Qb + (size_t)(qbase1 + l31) * DK + kd * 16 + hi * 8);
    }

    f32x16 oA0 = (f32x16)0.0f, oA1 = (f32x16)0.0f;
    f32x16 oB0 = (f32x16)0.0f, oB1 = (f32x16)0.0f;
    float mrunA = -3e38f, lrunA = 0.0f;
    float mrunB = -3e38f, lrunB = 0.0f;

    // Stage tile into buffer slot b_: 256 threads x 2 chunks (K and V each 8KB).
#define STAGE(tile_, b_) do {                                                          \
    int kv0_ = (tile_) * KVB;                                                          \
    _Pragma("unroll")                                                                  \
    for (int i_ = 0; i_ < 2; ++i_) {                                                   \
        int c_ = t + 256 * i_;                                                         \
        int row_ = c_ >> 3, kc_ = c_ & 7;                                              \
        int sw_ = (kc_ ^ (row_ & 7)) * 8;                                              \
        __builtin_amdgcn_global_load_lds(                                              \
            (const __attribute__((address_space(1))) void*)(Kb + (size_t)(kv0_ + row_) * DK + sw_), \
            (__attribute__((address_space(3))) void*)(lds + (b_) * 8192 + c_ * 16), 16, 0, 0);      \
        __builtin_amdgcn_global_load_lds(                                              \
            (const __attribute__((address_space(1))) void*)(Vt + (size_t)row_ * SEQ + kv0_ + sw_),  \
            (__attribute__((address_space(3))) void*)(lds + 24576 + (b_) * 8192 + c_ * 16), 16, 0, 0); \
    }                                                                                  \
} while (0)

    int swz7 = l31 & 7;
    int cofs0 = ((0 + hi) ^ swz7) << 4;
    int cofs1 = ((2 + hi) ^ swz7) << 4;
    int cofs2 = ((4 + hi) ^ swz7) << 4;
    int cofs3 = ((6 + hi) ^ swz7) << 4;

    // Prologue: stage tiles 0 and 1; wait only tile 0 (4 loads/thread in flight -> 2 remain).
    STAGE(0, 0);
    STAGE(1, 1);
    asm volatile("s_waitcnt vmcnt(4)" ::: "memory");
    __builtin_amdgcn_s_barrier();

    int b0 = 0, b1 = 1, b2 = 2;

    for (int kt = 0; kt < NT; ++kt) {
        if (kt + 2 < NT)
            STAGE(kt + 2, b2);

        const unsigned char* kb = lds + b0 * 8192;
        const unsigned char* vb = lds + 24576 + b0 * 8192;
        const unsigned char* kr0 = kb + l31 * 128;
        const unsigned char* kr1 = kb + (32 + l31) * 128;
        const unsigned char* vr0 = vb + l31 * 128;
        const unsigned char* vr1 = vb + (32 + l31) * 128;

        // ---- K frags (shared by both subtiles) ----
        bf16x8 ak00 = *(const bf16x8*)(kr0 + cofs0);
        bf16x8 ak01 = *(const bf16x8*)(kr0 + cofs1);
        bf16x8 ak02 = *(const bf16x8*)(kr0 + cofs2);
        bf16x8 ak03 = *(const bf16x8*)(kr0 + cofs3);
        bf16x8 ak10 = *(const bf16x8*)(kr1 + cofs0);
        bf16x8 ak11 = *(const bf16x8*)(kr1 + cofs1);
        bf16x8 ak12 = *(const bf16x8*)(kr1 + cofs2);
        bf16x8 ak13 = *(const bf16x8*)(kr1 + cofs3);

        // ---- S^T = K Q^T for subtiles A and B (K frags reused) ----
        f32x16 scA0 = (f32x16)0.0f, scA1 = (f32x16)0.0f;
        f32x16 scB0 = (f32x16)0.0f, scB1 = (f32x16)0.0f;
        __builtin_amdgcn_s_setprio(1);
        scA0 = __builtin_amdgcn_mfma_f32_32x32x16_bf16(ak00, aqA[0], scA0, 0, 0, 0);
        scA1 = __builtin_amdgcn_mfma_f32_32x32x16_bf16(ak10, aqA[0], scA1, 0, 0, 0);
        scB0 = __builtin_amdgcn_mfma_f32_32x32x16_bf16(ak00, aqB[0], scB0, 0, 0, 0);
        scB1 = __builtin_amdgcn_mfma_f32_32x32x16_bf16(ak10, aqB[0], scB1, 0, 0, 0);
        scA0 = __builtin_amdgcn_mfma_f32_32x32x16_bf16(ak01, aqA[1], scA0, 0, 0, 0);
        scA1 = __builtin_amdgcn_mfma_f32_32x32x16_bf16(ak11, aqA[1], scA1, 0, 0, 0);
        scB0 = __builtin_amdgcn_mfma_f32_32x32x16_bf16(ak01, aqB[1], scB0, 0, 0, 0);
        scB1 = __builtin_amdgcn_mfma_f32_32x32x16_bf16(ak11, aqB[1], scB1, 0, 0, 0);
        scA0 = __builtin_amdgcn_mfma_f32_32x32x16_bf16(ak02, aqA[2], scA0, 0, 0, 0);
        scA1 = __builtin_amdgcn_mfma_f32_32x32x16_bf16(ak12, aqA[2], scA1, 0, 0, 0);
        scB0 = __builtin_amdgcn_mfma_f32_32x32x16_bf16(ak02, aqB[2], scB0, 0, 0, 0);
        scB1 = __builtin_amdgcn_mfma_f32_32x32x16_bf16(ak12, aqB[2], scB1, 0, 0, 0);
        scA0 = __builtin_amdgcn_mfma_f32_32x32x16_bf16(ak03, aqA[3], scA0, 0, 0, 0);
        scA1 = __builtin_amdgcn_mfma_f32_32x32x16_bf16(ak13, aqA[3], scA1, 0, 0, 0);
        scB0 = __builtin_amdgcn_mfma_f32_32x32x16_bf16(ak03, aqB[3], scB0, 0, 0, 0);
        scB1 = __builtin_amdgcn_mfma_f32_32x32x16_bf16(ak13, aqB[3], scB1, 0, 0, 0);
        __builtin_amdgcn_s_setprio(0);

        // ---- V^T frags (shared by both subtiles); latency hides under softmax ----
        bf16x8 av00 = *(const bf16x8*)(vr0 + cofs0);
        bf16x8 av01 = *(const bf16x8*)(vr0 + cofs1);
        bf16x8 av02 = *(const bf16x8*)(vr0 + cofs2);
        bf16x8 av03 = *(const bf16x8*)(vr0 + cofs3);
        bf16x8 av10 = *(const bf16x8*)(vr1 + cofs0);
        bf16x8 av11 = *(const bf16x8*)(vr1 + cofs1);
        bf16x8 av12 = *(const bf16x8*)(vr1 + cofs2);
        bf16x8 av13 = *(const bf16x8*)(vr1 + cofs3);

        // ================= subtile A: softmax + PV =================
        {
            float mx = fmaxf(vmax16(scA0), vmax16(scA1));
            mx = fmaxf(mx, __shfl_xor(mx, 32));
            if (!__all(mx <= mrunA + 8.0f)) {
                float mnew = fmaxf(mrunA, mx);
                float al;  EXP2(al, mrunA - mnew);
                lrunA *= al;
                #pragma unroll
                for (int i = 0; i < 16; ++i) { oA0[i] *= al; oA1[i] *= al; }
                mrunA = mnew;
            }
            #pragma unroll
            for (int i = 0; i < 16; ++i) { float p; EXP2(p, scA0[i] - mrunA); scA0[i] = p; }
            #pragma unroll
            for (int i = 0; i < 16; ++i) { float p; EXP2(p, scA1[i] - mrunA); scA1[i] = p; }
            float r0 = 0.f, r1 = 0.f, r2 = 0.f, r3 = 0.f;
            #pragma unroll
            for (int i = 0; i < 4; ++i) {
                r0 += scA0[i] + scA1[i];     r1 += scA0[4+i] + scA1[4+i];
                r2 += scA0[8+i] + scA1[8+i]; r3 += scA0[12+i] + scA1[12+i];
            }
            float rs = (r0 + r1) + (r2 + r3);
            rs += __shfl_xor(rs, 32);
            lrunA += rs;

            bf16x8 pf0 = make_pf(scA0[0], scA0[1], scA0[2],  scA0[3],  scA0[4],  scA0[5],  scA0[6],  scA0[7]);
            bf16x8 pf1 = make_pf(scA0[8], scA0[9], scA0[10], scA0[11], scA0[12], scA0[13], scA0[14], scA0[15]);
            bf16x8 pf2 = make_pf(scA1[0], scA1[1], scA1[2],  scA1[3],  scA1[4],  scA1[5],  scA1[6],  scA1[7]);
            bf16x8 pf3 = make_pf(scA1[8], scA1[9], scA1[10], scA1[11], scA1[12], scA1[13], scA1[14], scA1[15]);

            __builtin_amdgcn_s_setprio(1);
            oA0 = __builtin_amdgcn_mfma_f32_32x32x16_bf16(av00, pf0, oA0, 0, 0, 0);
            oA1 = __builtin_amdgcn_mfma_f32_32x32x16_bf16(av10, pf0, oA1, 0, 0, 0);
            oA0 = __builtin_amdgcn_mfma_f32_32x32x16_bf16(av01, pf1, oA0, 0, 0, 0);
            oA1 = __builtin_amdgcn_mfma_f32_32x32x16_bf16(av11, pf1, oA1, 0, 0, 0);
            oA0 = __builtin_amdgcn_mfma_f32_32x32x16_bf16(av02, pf2, oA0, 0, 0, 0);
            oA1 = __builtin_amdgcn_mfma_f32_32x32x16_bf16(av12, pf2, oA1, 0, 0, 0);
            oA0 = __builtin_amdgcn_mfma_f32_32x32x16_bf16(av03, pf3, oA0, 0, 0, 0);
            oA1 = __builtin_amdgcn_mfma_f32_32x32x16_bf16(av13, pf3, oA1, 0, 0, 0);
            __builtin_amdgcn_s_setprio(0);
        }

        // ================= subtile B: softmax + PV =================
        {
            float mx = fmaxf(vmax16(scB0), vmax16(scB1));
            mx = fmaxf(mx, __shfl_xor(mx, 32));
            if (!__all(mx <= mrunB + 8.0f)) {
                float mnew = fmaxf(mrunB, mx);
                float al;  EXP2(al, mrunB - mnew);
                lrunB *= al;
                #pragma unroll
                for (int i = 0; i < 16; ++i) { oB0[i] *= al; oB1[i] *= al; }
                mrunB = mnew;
            }
            #pragma unroll
            for (int i = 0; i < 16; ++i) { float p; EXP2(p, scB0[i] - mrunB); scB0[i] = p; }
            #pragma unroll
            for (int i = 0; i < 16; ++i) { float p; EXP2(p, scB1[i] - mrunB); scB1[i] = p; }
            float r0 = 0.f, r1 = 0.f, r2 = 0.f, r3 = 0.f;
            #pragma unroll
            for (int i = 0; i < 4; ++i) {
                r0 += scB0[i] + scB1[i];     r1 += scB0[4+i] + scB1[4+i];
                r2 += scB0[8+i] + scB1[8+i]; r3 += scB0[12+i] + scB1[12+i];
            }
            float rs = (r0 + r1) + (r2 + r3);
            rs += __shfl_xor(rs, 32);
            lrunB += rs;

            bf16x8 pf0 = make_pf(scB0[0], scB0[1], scB0[2],  scB0[3],  scB0[4],  scB0[5],  scB0[6],  scB0[7]);
            bf16x8 pf1 = make_pf(scB0[8], scB0[9], scB0[10], scB0[11], scB0[12], scB0[13], scB0[14], scB0[15]);
            bf16x8 pf2 = make_pf(scB1[0], scB1[1], scB1[2],  scB1[3],  scB1[4],  scB1[5],  scB1[6],  scB1[7]);
            bf16x8 pf3 = make_pf(scB1[8], scB1[9], scB1[10], scB1[11], scB1[12], scB1[13], scB1[14], scB1[15]);

            __builtin_amdgcn_s_setprio(1);
            oB0 = __builtin_amdgcn_mfma_f32_32x32x16_bf16(av00, pf0, oB0, 0, 0, 0);
            oB1 = __builtin_amdgcn_mfma_f32_32x32x16_bf16(av10, pf0, oB1, 0, 0, 0);
            oB0 = __builtin_amdgcn_mfma_f32_32x32x16_bf16(av01, pf1, oB0, 0, 0, 0);
            oB1 = __builtin_amdgcn_mfma_f32_32x32x16_bf16(av11, pf1, oB1, 0, 0, 0);
            oB0 = __builtin_amdgcn_mfma_f32_32x32x16_bf16(av02, pf2, oB0, 0, 0, 0);
            oB1 = __builtin_amdgcn_mfma_f32_32x32x16_bf16(av12, pf2, oB1, 0, 0, 0);
            oB0 = __builtin_amdgcn_mfma_f32_32x32x16_bf16(av03, pf3, oB0, 0, 0, 0);
            oB1 = __builtin_amdgcn_mfma_f32_32x32x16_bf16(av13, pf3, oB1, 0, 0, 0);
            __builtin_amdgcn_s_setprio(0);
        }

        // ---- counted-vmcnt barrier: keep this iter's stage (4 loads) in flight ----
        if (kt + 2 < NT) {
            asm volatile("s_waitcnt vmcnt(4)" ::: "memory");   // retire next tile's loads
            __builtin_amdgcn_s_barrier();
        } else if (kt + 1 < NT) {
            asm volatile("s_waitcnt vmcnt(0)" ::: "memory");   // drain for last tile
            __builtin_amdgcn_s_barrier();
        }
        int tb = b0; b0 = b1; b1 = b2; b2 = tb;
    }
#undef STAGE

    // ---- epilogue: direct f32x4 stores for both subtiles ----
    int b = bh >> 4, h = bh & 15;
    {
        float rl = 1.0f / lrunA;
        float* dst = out + ((size_t)b * SEQ + qbase0 + l31) * D_MODEL + h * DK;
        #pragma unroll
        for (int g = 0; g < 4; ++g) {
            int d0 = 8 * g + 4 * hi;
            f32x4 v0 = { oA0[4*g] * rl, oA0[4*g+1] * rl, oA0[4*g+2] * rl, oA0[4*g+3] * rl };
            *(f32x4*)(dst + d0) = v0;
            f32x4 v1 = { oA1[4*g] * rl, oA1[4*g+1] * rl, oA1[4*g+2] * rl, oA1[4*g+3] * rl };
            *(f32x4*)(dst + 32 + d0) = v1;
        }
    }
    {
        float rl = 1.0f / lrunB;
        float* dst = out + ((size_t)b * SEQ + qbase1 + l31) * D_MODEL + h * DK;
        #pragma unroll
        for (int g = 0; g < 4; ++g) {
            int d0 = 8 * g + 4 * hi;
            f32x4 v0 = { oB0[4*g] * rl, oB0[4*g+1] * rl, oB0[4*g+2] * rl, oB0[4*g+3] * rl };
            *(f32x4*)(dst + d0) = v0;
            f32x4 v1 = { oB1[4*g] * rl, oB1[4*g+1] * rl, oB1[4*g+2] * rl, oB1[4*g+3] * rl };
            *(f32x4*)(dst + 32 + d0) = v1;
        }
    }
}

extern "C" void kernel_launch(void* const* d_in, const int* in_sizes, int n_in,
                              void* d_out, int out_size, void* d_ws, size_t ws_size,
                              hipStream_t stream) {
    const float* x  = (const float*)d_in[0];
    const float* Wq = (const float*)d_in[1];
    const float* bq = (const float*)d_in[2];
    const float* Wk = (const float*)d_in[3];
    const float* bk = (const float*)d_in[4];
    const float* Wv = (const float*)d_in[5];
    const float* bv = (const float*)d_in[6];
    float* out = (float*)d_out;

    unsigned short* xb  = (unsigned short*)d_ws;                       // 16 MB
    unsigned short* wt  = xb + (size_t)MTOT * D_MODEL;                 // 6 MB
    unsigned short* qkv = wt + (size_t)3 * D_MODEL * D_MODEL;          // 48 MB

    cvt_fused_kernel<<<dim3(7168), dim3(256), 0, stream>>>(x, Wq, Wk, Wv, xb, wt);
    qkv_gemm_kernel<<<dim3(24, 32), dim3(256), 0, stream>>>(xb, wt, bq, bk, bv, qkv);
    attn_kernel<<<dim3(64, 8), dim3(256), 0, stream>>>(qkv, out);
}